// Round 8
// baseline (330.942 us; speedup 1.0000x reference)
//
#include <hip/hip_runtime.h>
#include <cstdint>

typedef unsigned short u16;
typedef short s8v __attribute__((ext_vector_type(8)));
typedef float f4v __attribute__((ext_vector_type(4)));

// fp32 -> bf16 round-to-nearest-even (bit trick)
__device__ __forceinline__ u16 f2b(float f) {
  uint32_t u = __float_as_uint(f);
  u = (u + 0x7FFFu + ((u >> 16) & 1u)) >> 16;
  return (u16)u;
}

// pack two f32 -> bf16x2 (RNE) in one instruction (T12 recipe; no builtin)
__device__ __forceinline__ uint32_t pk2(float a, float b) {
  uint32_t r;
  asm("v_cvt_pk_bf16_f32 %0, %1, %2" : "=v"(r) : "v"(a), "v"(b));
  return r;
}

// async global->LDS, 16B per lane (wave-uniform LDS base + lane*16 layout)
__device__ __forceinline__ void gload16(const u16* g, u16* l) {
  __builtin_amdgcn_global_load_lds(
      (const __attribute__((address_space(1))) void*)g,
      (__attribute__((address_space(3))) void*)l, 16, 0, 0);
}

// ---------------------------------------------------------------------------
// Fused prep kernel (unchanged from round 7)
// blocks: [0,4096) conv_x | [4096,4864) convT_w | [4864,5120) convT_wo |
//         [5120,5136) conv_bias
// ---------------------------------------------------------------------------
__global__ void prep(const float* __restrict__ x, u16* __restrict__ xb,
                     const float* __restrict__ WQ, const float* __restrict__ WK,
                     const float* __restrict__ WV, const float* __restrict__ WO,
                     u16* __restrict__ WTqkv, u16* __restrict__ WOT,
                     const float* __restrict__ bQ, const float* __restrict__ bK,
                     const float* __restrict__ bV, const float* __restrict__ bO,
                     float* __restrict__ bqkv, float* __restrict__ bsum) {
  __shared__ u16 tile[64][65];
  const int bid = blockIdx.x;
  const int tid = threadIdx.x;

  if (bid < 4096) {                       // x fp32 -> bf16, 4 elems/thread
    int i = bid * 256 + tid;
    float4 v = ((const float4*)x)[i];
    uint2 o;
    o.x = (uint32_t)f2b(v.x) | ((uint32_t)f2b(v.y) << 16);
    o.y = (uint32_t)f2b(v.z) | ((uint32_t)f2b(v.w) << 16);
    ((uint2*)xb)[i] = o;
  } else if (bid < 4864) {                // W_{Q,K,V} -> WTqkv (B^T), 64x64 transpose
    int sub = bid - 4096;
    int w = sub >> 8, sub2 = sub & 255;
    const float* W = (w == 0) ? WQ : (w == 1) ? WK : WV;
    u16* dst = WTqkv + (size_t)w * 1024 * 1024;
    const int m0 = (sub2 & 15) * 64;
    const int h  = sub2 >> 4;
    const int c  = tid & 63;
    const int r4 = tid >> 6;
    const float* Wh = W + (size_t)h * 65536;
    for (int i = 0; i < 16; ++i) {
      int lm = i * 4 + r4;
      tile[lm][c] = f2b(Wh[(size_t)(m0 + lm) * 64 + c]);
    }
    __syncthreads();
    for (int i = 0; i < 16; ++i) {
      int dd = i * 4 + r4;
      dst[((size_t)h * 64 + dd) * 1024 + m0 + c] = tile[c][dd];
    }
  } else if (bid < 5120) {                // W_O flat [1024][1024] -> WOT[m][k]
    int sub = bid - 4864;
    const int k0 = (sub & 15) * 64;
    const int m0 = (sub >> 4) * 64;
    const int c  = tid & 63;
    const int r4 = tid >> 6;
    for (int i = 0; i < 16; ++i) {
      int lk = i * 4 + r4;
      tile[lk][c] = f2b(WO[(size_t)(k0 + lk) * 1024 + m0 + c]);
    }
    __syncthreads();
    for (int i = 0; i < 16; ++i) {
      int lm = i * 4 + r4;
      WOT[(size_t)(m0 + lm) * 1024 + k0 + c] = tile[c][lm];
    }
  } else {                                // biases
    int t = (bid - 5120) * 256 + tid;
    if (t < 1024)       bqkv[t] = bQ[t];
    else if (t < 2048)  bqkv[t] = bK[t - 1024];
    else if (t < 3072)  bqkv[t] = bV[t - 2048];
    else {
      int m = t - 3072;
      float s = 0.f;
      for (int hh = 0; hh < 16; ++hh) s += bO[hh * 1024 + m];
      bsum[m] = s;
    }
  }
}

// V columns of QKV [4096][3072] (cols 2048..3071) -> VT[(h*64+d)][token] bf16.
__global__ void convT_v(const u16* __restrict__ QKV, u16* __restrict__ VT) {
  __shared__ u16 tile[64][65];
  const int r0 = blockIdx.x * 64;
  const int c0 = blockIdx.y * 64;
  const int c  = threadIdx.x & 63;
  const int r4 = threadIdx.x >> 6;
  for (int i = 0; i < 16; ++i) {
    int lr = i * 4 + r4;
    tile[lr][c] = QKV[(size_t)(r0 + lr) * 3072 + 2048 + c0 + c];
  }
  __syncthreads();
  for (int i = 0; i < 16; ++i) {
    int lc = i * 4 + r4;
    VT[(size_t)(c0 + lc) * 4096 + r0 + c] = tile[c][lc];
  }
}

// ---------------------------------------------------------------------------
// bf16 MFMA GEMM: C = (A * BT^T + bias[col]) * (col<scale_cols ? 0.125 : 1)
// 128xBN tile, BK=32, 4 waves (2x2). Round-8: 2-phase pipeline (T3 minimum
// recipe): double-buffered LDS, STAGE(next buf) issued BEFORE ds_read+MFMA of
// current buf, ONE barrier per K-step -> global-load latency hides under the
// MFMA block instead of being drained raw at the barrier.
// BN=128 (QKV proj) or BN=64 (out-proj: 512 blocks = 2/CU instead of 1/CU).
// ---------------------------------------------------------------------------
template<bool OUT_F32, int BN>
__global__ void gemm_bt(const u16* __restrict__ A, const u16* __restrict__ BT,
                        const float* __restrict__ bias, void* __restrict__ Cout,
                        int N, int K, int scale_cols) {
  __shared__ __align__(16) u16 sA[2][128 * 32];
  __shared__ __align__(16) u16 sB[2][BN * 32];
  const int tid  = threadIdx.x;
  const int lane = tid & 63, wave = tid >> 6;
  const int wm = wave >> 1, wn = wave & 1;
  const int lq = lane & 15, quad = lane >> 4;
  const int m0 = blockIdx.y * 128, n0 = blockIdx.x * BN;
  constexpr int NJ = BN / 32;            // MFMA col-tiles per wave

  f4v acc[4][NJ] = {};

  auto STAGE = [&](int buf, int k0) {
    // A tile 128x32: 512 16B segs, 2/thread
    for (int i = 0; i < 2; ++i) {
      int s = tid + i * 256;
      int row = s >> 2, part = s & 3;
      gload16(A + (size_t)(m0 + row) * K + k0 + part * 8, &sA[buf][s * 8]);
    }
    // B tile BNx32: BN*4 segs
    if (BN == 128) {
      for (int i = 0; i < 2; ++i) {
        int s = tid + i * 256;
        int row = s >> 2, part = s & 3;
        gload16(BT + (size_t)(n0 + row) * K + k0 + part * 8, &sB[buf][s * 8]);
      }
    } else {                             // BN=64: exactly 256 segs, 1/thread
      int row = tid >> 2, part = tid & 3;
      gload16(BT + (size_t)(n0 + row) * K + k0 + part * 8, &sB[buf][tid * 8]);
    }
  };

  STAGE(0, 0);
  __syncthreads();                       // compiler drains vmcnt before barrier
  int cur = 0;
  for (int k0 = 0; k0 < K; k0 += 32) {
    if (k0 + 32 < K) STAGE(cur ^ 1, k0 + 32);   // issue next-tile loads FIRST
    s8v af[4], bfr[NJ];
    for (int i = 0; i < 4; ++i)
      af[i]  = *(const s8v*)&sA[cur][(wm * 64 + i * 16 + lq) * 32 + quad * 8];
    for (int j = 0; j < NJ; ++j)
      bfr[j] = *(const s8v*)&sB[cur][(wn * (BN / 2) + j * 16 + lq) * 32 + quad * 8];
    for (int i = 0; i < 4; ++i)
      for (int j = 0; j < NJ; ++j)
        acc[i][j] = __builtin_amdgcn_mfma_f32_16x16x32_bf16(af[i], bfr[j], acc[i][j], 0, 0, 0);
    __syncthreads();                     // next-tile loads overlapped the MFMAs
    cur ^= 1;
  }

  for (int i = 0; i < 4; ++i)
    for (int j = 0; j < NJ; ++j) {
      int row = m0 + wm * 64 + i * 16 + quad * 4;
      int col = n0 + wn * (BN / 2) + j * 16 + lq;
      float bb = bias[col];
      float sc = (col < scale_cols) ? 0.125f : 1.0f;
      for (int r = 0; r < 4; ++r) {
        float v = (acc[i][j][r] + bb) * sc;
        if (OUT_F32) ((float*)Cout)[(size_t)(row + r) * N + col] = v;
        else         ((u16*)Cout)[(size_t)(row + r) * N + col] = f2b(v);
      }
    }
}

// ---------------------------------------------------------------------------
// Flash attention (causal). 1 wave, 2 adjacent 16-query tiles, KVBLK=64.
// Round-8: SPLIT-K. Heavy pairs (u>=32, >=17 chunks) are split into two
// key-range halves handled by different blocks writing fp32 partials
// (z unnormalized, m, l); light pairs unchanged. Grid 2048 -> 3072 waves
// (12/CU). Job->slot mapping gives each CU the triple {unsplit u=s0,
// half0(63-s0), half1(63-s0)} x 4 combos = constant ~33 chunks -> flat
// occupancy, no tail. combine() merges halves for rows q>=1024.
// SPLIT=false is the round-7 path (ws_size fallback).
// ---------------------------------------------------------------------------
template<bool SPLIT>
__global__ __launch_bounds__(64, 4) void attn_fwd(const u16* __restrict__ QKV,
                                                  const u16* __restrict__ VT,
                                                  u16* __restrict__ Z,
                                                  float* __restrict__ Zp,
                                                  float2* __restrict__ ml) {
  __shared__ __align__(16) u16 sP[2][2][16 * 72];   // [tile][pingpong]
  const int lane = threadIdx.x;
  const int lq = lane & 15, quad = lane >> 4;

  int g, u, c_lo, c_hi, part_p;
  const int id  = blockIdx.x;
  const int xcd = id & 7;
  if (SPLIT) {
    const int slot = id >> 3;            // 0..383
    const int cwx  = slot / 96;          // combo-within-XCD 0..3
    const int rr   = slot % 96;
    const int s0   = rr & 31;
    const int role = rr >> 5;            // 0: unsplit, 1: half0, 2: half1
    g = xcd + 8 * cwx;
    if (role == 0) { u = s0; c_lo = 0; c_hi = u / 2 + 1; part_p = -1; }
    else {
      u = 63 - s0;
      const int nc = u / 2 + 1, nc0 = nc >> 1;
      part_p = role - 1;
      c_lo = part_p ? nc0 : 0;
      c_hi = part_p ? nc  : nc0;
    }
  } else {
    const int slot = id >> 3;
    g = xcd + 8 * (slot >> 6);
    const int ss = slot & 63;
    u = (ss < 32) ? (63 - ss) : (ss - 32);
    c_lo = 0; c_hi = u / 2 + 1; part_p = -1;
  }
  const int nfull = u / 2 + 1;           // true last chunk = nfull-1 (masked)
  const int h = g & 15, b = g >> 4;
  const int qA = u * 32, qB = qA + 16;

  const int RS = 3072;
  const u16* base = QKV + (size_t)b * 2048 * RS;
  const u16* Qb  = base + h * 64;
  const u16* Kb  = base + 1024 + h * 64;
  const u16* VTb = VT + (size_t)h * 64 * 4096 + (size_t)b * 2048;

  // Q frags (B-operand): lane holds Q[q+lq][d = 32*half + quad*8 + j]
  s8v qfA0 = *(const s8v*)&Qb[(size_t)(qA + lq) * RS + quad * 8];
  s8v qfA1 = *(const s8v*)&Qb[(size_t)(qA + lq) * RS + 32 + quad * 8];
  s8v qfB0 = *(const s8v*)&Qb[(size_t)(qB + lq) * RS + quad * 8];
  s8v qfB1 = *(const s8v*)&Qb[(size_t)(qB + lq) * RS + 32 + quad * 8];

  f4v zA[4] = {}, zB[4] = {};
  float mA = -3.0e38f, lA = 0.f, mB = -3.0e38f, lB = 0.f;

  s8v kf[8], vf[8];   // single buffers: K rows / V cols of the current chunk

#define LOADK(c_) do {                                                        \
    const int kk0_ = (c_) * 64;                                               \
    _Pragma("unroll")                                                         \
    for (int i_ = 0; i_ < 4; ++i_) {                                          \
      const u16* kr_ = &Kb[(size_t)(kk0_ + 16 * i_ + lq) * RS + quad * 8];    \
      kf[2 * i_]     = *(const s8v*)kr_;                                      \
      kf[2 * i_ + 1] = *(const s8v*)(kr_ + 32);                               \
    }                                                                         \
  } while (0)

#define LOADV(c_) do {                                                        \
    const int kk0_ = (c_) * 64;                                               \
    _Pragma("unroll")                                                         \
    for (int d_ = 0; d_ < 4; ++d_) {                                          \
      const u16* vr_ = &VTb[(size_t)(d_ * 16 + lq) * 4096 + kk0_ + quad * 8]; \
      vf[d_]     = *(const s8v*)vr_;                                          \
      vf[d_ + 4] = *(const s8v*)(vr_ + 32);                                   \
    }                                                                         \
  } while (0)

  // softmax of 64-key chunk c for one tile (swapped layout) + packed P write
  auto SMW = [&](int c, int qt0, float& mrow, float& lsum, f4v (&zacc)[4],
                 u16* sPt, f4v (&sc)[4]) {
    float sv[4][4];
    for (int i = 0; i < 4; ++i)
      for (int r = 0; r < 4; ++r) sv[i][r] = sc[i][r];
    if (c == nfull - 1) {               // only the true last chunk crosses diag
      const int kb = c * 64;
      for (int i = 0; i < 4; ++i)
        for (int r = 0; r < 4; ++r)
          if (kb + 16 * i + quad * 4 + r > qt0 + lq) sv[i][r] = -3.0e38f;
    }
    float lmax = sv[0][0];
    for (int i = 0; i < 4; ++i)
      for (int r = 0; r < 4; ++r) lmax = fmaxf(lmax, sv[i][r]);
    if (!__all(lmax <= mrow + 8.0f)) {  // defer-max, THR=8
      float t = lmax;
      t = fmaxf(t, __shfl_xor(t, 16, 64));
      t = fmaxf(t, __shfl_xor(t, 32, 64));
      float mnew = fmaxf(mrow, t);
      float al = __expf(mrow - mnew);
      mrow = mnew;
      lsum *= al;
      float alr[4];
      for (int r = 0; r < 4; ++r) alr[r] = __shfl(al, quad * 4 + r, 16);
      for (int dc = 0; dc < 4; ++dc)
        for (int r = 0; r < 4; ++r) zacc[dc][r] *= alr[r];
    }
    float acc = 0.f;
    float p[4][4];
    for (int i = 0; i < 4; ++i)
      for (int r = 0; r < 4; ++r) {
        p[i][r] = __expf(sv[i][r] - mrow);
        acc += p[i][r];
      }
    lsum += acc;
    for (int i = 0; i < 4; ++i) {
      uint2 w;
      w.x = pk2(p[i][0], p[i][1]);
      w.y = pk2(p[i][2], p[i][3]);
      *(uint2*)&sPt[lq * 72 + 16 * i + quad * 4] = w;
    }
  };

#define QK(aA_, aB_) do {                                                     \
    _Pragma("unroll")                                                         \
    for (int i_ = 0; i_ < 4; ++i_) {                                          \
      aA_[i_] = __builtin_amdgcn_mfma_f32_16x16x32_bf16(kf[2*i_],   qfA0, aA_[i_], 0, 0, 0); \
      aA_[i_] = __builtin_amdgcn_mfma_f32_16x16x32_bf16(kf[2*i_+1], qfA1, aA_[i_], 0, 0, 0); \
      aB_[i_] = __builtin_amdgcn_mfma_f32_16x16x32_bf16(kf[2*i_],   qfB0, aB_[i_], 0, 0, 0); \
      aB_[i_] = __builtin_amdgcn_mfma_f32_16x16x32_bf16(kf[2*i_+1], qfB1, aB_[i_], 0, 0, 0); \
    }                                                                         \
  } while (0)

  auto PV = [&](int pb) {
    s8v pA0 = *(const s8v*)&sP[0][pb][lq * 72 + quad * 8];
    s8v pA1 = *(const s8v*)&sP[0][pb][lq * 72 + 32 + quad * 8];
    s8v pB0 = *(const s8v*)&sP[1][pb][lq * 72 + quad * 8];
    s8v pB1 = *(const s8v*)&sP[1][pb][lq * 72 + 32 + quad * 8];
#pragma unroll
    for (int d_ = 0; d_ < 4; ++d_) {
      zA[d_] = __builtin_amdgcn_mfma_f32_16x16x32_bf16(pA0, vf[d_],     zA[d_], 0, 0, 0);
      zA[d_] = __builtin_amdgcn_mfma_f32_16x16x32_bf16(pA1, vf[d_ + 4], zA[d_], 0, 0, 0);
      zB[d_] = __builtin_amdgcn_mfma_f32_16x16x32_bf16(pB0, vf[d_],     zB[d_], 0, 0, 0);
      zB[d_] = __builtin_amdgcn_mfma_f32_16x16x32_bf16(pB1, vf[d_ + 4], zB[d_], 0, 0, 0);
    }
  };

  LOADK(c_lo);
  { // first chunk of range: QK + softmax + P write (PV deferred)
    f4v aA[4] = {}, aB[4] = {};
    __builtin_amdgcn_s_setprio(1);
    QK(aA, aB);
    __builtin_amdgcn_s_setprio(0);
    if (c_lo + 1 < c_hi) LOADK(c_lo + 1);
    LOADV(c_lo);
    SMW(c_lo, qA, mA, lA, zA, sP[0][c_lo & 1], aA);
    SMW(c_lo, qB, mB, lB, zB, sP[1][c_lo & 1], aB);
    asm volatile("" ::: "memory");
  }

  for (int c = c_lo + 1; c < c_hi; ++c) {
    f4v aA[4] = {}, aB[4] = {};
    __builtin_amdgcn_s_setprio(1);
    QK(aA, aB);                         // kf = K(c)
    PV((c + 1) & 1);                    // reads P(c-1) + vf = V(c-1)
    __builtin_amdgcn_s_setprio(0);
    asm volatile("" ::: "memory");
    if (c + 1 < c_hi) LOADK(c + 1);
    LOADV(c);
    SMW(c, qA, mA, lA, zA, sP[0][c & 1], aA);
    SMW(c, qB, mB, lB, zB, sP[1][c & 1], aB);
    asm volatile("" ::: "memory");
  }

  { // drain: PV of last chunk in range
    __builtin_amdgcn_s_setprio(1);
    PV((c_hi - 1) & 1);
    __builtin_amdgcn_s_setprio(0);
  }
#undef QK
#undef LOADK
#undef LOADV

  // sum reduction across the 4 quad-lanes of each row
  lA += __shfl_xor(lA, 16, 64); lA += __shfl_xor(lA, 32, 64);
  lB += __shfl_xor(lB, 16, 64); lB += __shfl_xor(lB, 32, 64);

  if (!SPLIT || part_p < 0) {           // full pair: normalize + write Z bf16
    float invA[4], invB[4];
    for (int r = 0; r < 4; ++r) {
      invA[r] = 1.0f / __shfl(lA, quad * 4 + r, 16);
      invB[r] = 1.0f / __shfl(lB, quad * 4 + r, 16);
    }
    for (int dc = 0; dc < 4; ++dc)
      for (int r = 0; r < 4; ++r) {
        size_t rowA = (size_t)b * 2048 + qA + quad * 4 + r;
        size_t rowB = (size_t)b * 2048 + qB + quad * 4 + r;
        Z[rowA * 1024 + h * 64 + dc * 16 + lq] = f2b(zA[dc][r] * invA[r]);
        Z[rowB * 1024 + h * 64 + dc * 16 + lq] = f2b(zB[dc][r] * invB[r]);
      }
  } else {                              // half pair: write fp32 partials
    float* ZpP = Zp + (size_t)part_p * (32768 * 64);
    const int prA = g * 1024 + (qA - 1024) + quad * 4;   // qA >= 1024 here
    const int prB = g * 1024 + (qB - 1024) + quad * 4;
    for (int dc = 0; dc < 4; ++dc)
      for (int r = 0; r < 4; ++r) {
        ZpP[(size_t)(prA + r) * 64 + dc * 16 + lq] = zA[dc][r];
        ZpP[(size_t)(prB + r) * 64 + dc * 16 + lq] = zB[dc][r];
      }
    if (quad == 0) {                    // lane lq owns row q0+lq's (m,l)
      ml[(size_t)part_p * 32768 + g * 1024 + (qA - 1024) + lq] = make_float2(mA, lA);
      ml[(size_t)part_p * 32768 + g * 1024 + (qB - 1024) + lq] = make_float2(mB, lB);
    }
  }
}

// ---------------------------------------------------------------------------
// Combine split-K halves for rows q in [1024, 2048) of each (b,h).
// out = (z0*w0 + z1*w1) / (l0*w0 + l1*w1), wp = exp(mp - max(m0,m1)). Exact.
// 524288 threads: each handles 4 d's of one partial row.
// ---------------------------------------------------------------------------
__global__ void combine(const float* __restrict__ Zp, const float2* __restrict__ ml,
                        u16* __restrict__ Z) {
  const int t = blockIdx.x * 256 + threadIdx.x;     // < 524288
  const int row = t >> 4;
  const int dseg = (t & 15) * 4;
  const float2 a = ml[row];
  const float2 c = ml[32768 + row];
  const float M  = fmaxf(a.x, c.x);
  const float w0 = __expf(a.x - M), w1 = __expf(c.x - M);
  const float inv = 1.0f / (a.y * w0 + c.y * w1);
  const float4 z0 = *(const float4*)&Zp[(size_t)row * 64 + dseg];
  const float4 z1 = *(const float4*)&Zp[(size_t)32768 * 64 + (size_t)row * 64 + dseg];
  const float o0 = (z0.x * w0 + z1.x * w1) * inv;
  const float o1 = (z0.y * w0 + z1.y * w1) * inv;
  const float o2 = (z0.z * w0 + z1.z * w1) * inv;
  const float o3 = (z0.w * w0 + z1.w * w1) * inv;
  const int g = row >> 10, qloc = row & 1023;
  const int bb = g >> 4, hh = g & 15;
  const size_t zoff = ((size_t)bb * 2048 + 1024 + qloc) * 1024 + hh * 64 + dseg;
  uint2 w;
  w.x = pk2(o0, o1);
  w.y = pk2(o2, o3);
  *(uint2*)&Z[zoff] = w;
}

// ---------------------------------------------------------------------------
// Launch
// ---------------------------------------------------------------------------
extern "C" void kernel_launch(void* const* d_in, const int* in_sizes, int n_in,
                              void* d_out, int out_size, void* d_ws, size_t ws_size,
                              hipStream_t stream) {
  const float* x  = (const float*)d_in[0];
  const float* WQ = (const float*)d_in[1];
  const float* bQ = (const float*)d_in[2];
  const float* WK = (const float*)d_in[3];
  const float* bK = (const float*)d_in[4];
  const float* WV = (const float*)d_in[5];
  const float* WO = (const float*)d_in[6];
  const float* bV = (const float*)d_in[7];
  const float* bO = (const float*)d_in[8];
  float* out = (float*)d_out;

  uint8_t* ws = (uint8_t*)d_ws;
  u16*   xb    = (u16*)(ws);                       //  8 MB  (dead after QKV GEMM)
  u16*   VTv   = (u16*)(ws);                       //  8 MB  V^T (reuses xb)
  u16*   WTqkv = (u16*)(ws + 8388608);             //  6 MB
  u16*   WOT   = (u16*)(ws + 14680064);            //  2 MB
  u16*   QKV   = (u16*)(ws + 16777216);            // 24 MB
  u16*   Zb    = (u16*)(ws + 41943040);            //  8 MB
  float* bqkv  = (float*)(ws + 50331648);          // 12 KB
  float* bsum  = (float*)(ws + 50343936);          //  4 KB
  float* Zp    = (float*)(ws + 50348032);          // 16 MB  split-K partials
  float2* mlp  = (float2*)(ws + 67125248);         // 512 KB (m,l) per partial row
  const bool do_split = ws_size >= 67649536ull;    // host-static; fallback if small

  // fused prep: conv_x + 3x convT_w + convT_wo + conv_bias
  prep<<<5136, 256, 0, stream>>>(x, xb, WQ, WK, WV, WO, WTqkv, WOT,
                                 bQ, bK, bV, bO, bqkv, bsum);
  // QKV projection: Q columns pre-scaled by 0.125 (exact in bf16)
  gemm_bt<false, 128><<<dim3(24, 32), 256, 0, stream>>>(xb, WTqkv, bqkv, (void*)QKV, 3072, 1024, 1024);
  // V transpose (xb dead; VT reuses its workspace)
  convT_v<<<dim3(64, 16), 256, 0, stream>>>(QKV, VTv);
  // attention
  if (do_split) {
    attn_fwd<true><<<dim3(3072, 1, 1), 64, 0, stream>>>(QKV, VTv, Zb, Zp, mlp);
    combine<<<2048, 256, 0, stream>>>(Zp, mlp, Zb);
  } else {
    attn_fwd<false><<<dim3(2048, 1, 1), 64, 0, stream>>>(QKV, VTv, Zb, Zp, mlp);
  }
  // output projection: [4096x1024] x [1024x1024] -> fp32 out (+ sum_h b_O)
  gemm_bt<true, 64><<<dim3(16, 32), 256, 0, stream>>>(Zb, WOT, bsum, (void*)out, 1024, 1024, 0);
}

// Round 9
// 236.044 us; speedup vs baseline: 1.4020x; 1.4020x over previous
//
#include <hip/hip_runtime.h>
#include <cstdint>

typedef unsigned short u16;
typedef short s8v __attribute__((ext_vector_type(8)));
typedef float f4v __attribute__((ext_vector_type(4)));

// fp32 -> bf16 round-to-nearest-even (bit trick)
__device__ __forceinline__ u16 f2b(float f) {
  uint32_t u = __float_as_uint(f);
  u = (u + 0x7FFFu + ((u >> 16) & 1u)) >> 16;
  return (u16)u;
}

// pack two f32 -> bf16x2 (RNE) in one instruction (T12 recipe; no builtin)
__device__ __forceinline__ uint32_t pk2(float a, float b) {
  uint32_t r;
  asm("v_cvt_pk_bf16_f32 %0, %1, %2" : "=v"(r) : "v"(a), "v"(b));
  return r;
}

// async global->LDS, 16B per lane (wave-uniform LDS base + lane*16 layout)
__device__ __forceinline__ void gload16(const u16* g, u16* l) {
  __builtin_amdgcn_global_load_lds(
      (const __attribute__((address_space(1))) void*)g,
      (__attribute__((address_space(3))) void*)l, 16, 0, 0);
}

// ---------------------------------------------------------------------------
// Fused prep kernel
// blocks: [0,4096) conv_x | [4096,4864) convT_w | [4864,5120) convT_wo |
//         [5120,5136) conv_bias
// ---------------------------------------------------------------------------
__global__ void prep(const float* __restrict__ x, u16* __restrict__ xb,
                     const float* __restrict__ WQ, const float* __restrict__ WK,
                     const float* __restrict__ WV, const float* __restrict__ WO,
                     u16* __restrict__ WTqkv, u16* __restrict__ WOT,
                     const float* __restrict__ bQ, const float* __restrict__ bK,
                     const float* __restrict__ bV, const float* __restrict__ bO,
                     float* __restrict__ bqkv, float* __restrict__ bsum) {
  __shared__ u16 tile[64][65];
  const int bid = blockIdx.x;
  const int tid = threadIdx.x;

  if (bid < 4096) {                       // x fp32 -> bf16, 4 elems/thread
    int i = bid * 256 + tid;
    float4 v = ((const float4*)x)[i];
    uint2 o;
    o.x = (uint32_t)f2b(v.x) | ((uint32_t)f2b(v.y) << 16);
    o.y = (uint32_t)f2b(v.z) | ((uint32_t)f2b(v.w) << 16);
    ((uint2*)xb)[i] = o;
  } else if (bid < 4864) {                // W_{Q,K,V} -> WTqkv (B^T), 64x64 transpose
    int sub = bid - 4096;
    int w = sub >> 8, sub2 = sub & 255;
    const float* W = (w == 0) ? WQ : (w == 1) ? WK : WV;
    u16* dst = WTqkv + (size_t)w * 1024 * 1024;
    const int m0 = (sub2 & 15) * 64;
    const int h  = sub2 >> 4;
    const int c  = tid & 63;
    const int r4 = tid >> 6;
    const float* Wh = W + (size_t)h * 65536;
    for (int i = 0; i < 16; ++i) {
      int lm = i * 4 + r4;
      tile[lm][c] = f2b(Wh[(size_t)(m0 + lm) * 64 + c]);
    }
    __syncthreads();
    for (int i = 0; i < 16; ++i) {
      int dd = i * 4 + r4;
      dst[((size_t)h * 64 + dd) * 1024 + m0 + c] = tile[c][dd];
    }
  } else if (bid < 5120) {                // W_O flat [1024][1024] -> WOT[m][k]
    int sub = bid - 4864;
    const int k0 = (sub & 15) * 64;
    const int m0 = (sub >> 4) * 64;
    const int c  = tid & 63;
    const int r4 = tid >> 6;
    for (int i = 0; i < 16; ++i) {
      int lk = i * 4 + r4;
      tile[lk][c] = f2b(WO[(size_t)(k0 + lk) * 1024 + m0 + c]);
    }
    __syncthreads();
    for (int i = 0; i < 16; ++i) {
      int lm = i * 4 + r4;
      WOT[(size_t)(m0 + lm) * 1024 + k0 + c] = tile[c][lm];
    }
  } else {                                // biases
    int t = (bid - 5120) * 256 + tid;
    if (t < 1024)       bqkv[t] = bQ[t];
    else if (t < 2048)  bqkv[t] = bK[t - 1024];
    else if (t < 3072)  bqkv[t] = bV[t - 2048];
    else {
      int m = t - 3072;
      float s = 0.f;
      for (int hh = 0; hh < 16; ++hh) s += bO[hh * 1024 + m];
      bsum[m] = s;
    }
  }
}

// V columns of QKV [4096][3072] (cols 2048..3071) -> VT[(h*64+d)][token] bf16.
__global__ void convT_v(const u16* __restrict__ QKV, u16* __restrict__ VT) {
  __shared__ u16 tile[64][65];
  const int r0 = blockIdx.x * 64;
  const int c0 = blockIdx.y * 64;
  const int c  = threadIdx.x & 63;
  const int r4 = threadIdx.x >> 6;
  for (int i = 0; i < 16; ++i) {
    int lr = i * 4 + r4;
    tile[lr][c] = QKV[(size_t)(r0 + lr) * 3072 + 2048 + c0 + c];
  }
  __syncthreads();
  for (int i = 0; i < 16; ++i) {
    int lc = i * 4 + r4;
    VT[(size_t)(c0 + lc) * 4096 + r0 + c] = tile[c][lc];
  }
}

// ---------------------------------------------------------------------------
// bf16 MFMA GEMM: C = (A * BT^T + bias[col]) * (col<scale_cols ? 0.125 : 1)
// 128xBN tile, BK=32, 4 waves (2x2). 2-phase pipeline: double-buffered LDS,
// STAGE(next) issued BEFORE ds_read+MFMA of current, one barrier per K-step.
// ---------------------------------------------------------------------------
template<bool OUT_F32, int BN>
__global__ void gemm_bt(const u16* __restrict__ A, const u16* __restrict__ BT,
                        const float* __restrict__ bias, void* __restrict__ Cout,
                        int N, int K, int scale_cols) {
  __shared__ __align__(16) u16 sA[2][128 * 32];
  __shared__ __align__(16) u16 sB[2][BN * 32];
  const int tid  = threadIdx.x;
  const int lane = tid & 63, wave = tid >> 6;
  const int wm = wave >> 1, wn = wave & 1;
  const int lq = lane & 15, quad = lane >> 4;
  const int m0 = blockIdx.y * 128, n0 = blockIdx.x * BN;
  constexpr int NJ = BN / 32;            // MFMA col-tiles per wave

  f4v acc[4][NJ] = {};

  auto STAGE = [&](int buf, int k0) {
    for (int i = 0; i < 2; ++i) {
      int s = tid + i * 256;
      int row = s >> 2, part = s & 3;
      gload16(A + (size_t)(m0 + row) * K + k0 + part * 8, &sA[buf][s * 8]);
    }
    if (BN == 128) {
      for (int i = 0; i < 2; ++i) {
        int s = tid + i * 256;
        int row = s >> 2, part = s & 3;
        gload16(BT + (size_t)(n0 + row) * K + k0 + part * 8, &sB[buf][s * 8]);
      }
    } else {                             // BN=64: exactly 256 segs, 1/thread
      int row = tid >> 2, part = tid & 3;
      gload16(BT + (size_t)(n0 + row) * K + k0 + part * 8, &sB[buf][tid * 8]);
    }
  };

  STAGE(0, 0);
  __syncthreads();                       // compiler drains vmcnt before barrier
  int cur = 0;
  for (int k0 = 0; k0 < K; k0 += 32) {
    if (k0 + 32 < K) STAGE(cur ^ 1, k0 + 32);   // issue next-tile loads FIRST
    s8v af[4], bfr[NJ];
    for (int i = 0; i < 4; ++i)
      af[i]  = *(const s8v*)&sA[cur][(wm * 64 + i * 16 + lq) * 32 + quad * 8];
    for (int j = 0; j < NJ; ++j)
      bfr[j] = *(const s8v*)&sB[cur][(wn * (BN / 2) + j * 16 + lq) * 32 + quad * 8];
    for (int i = 0; i < 4; ++i)
      for (int j = 0; j < NJ; ++j)
        acc[i][j] = __builtin_amdgcn_mfma_f32_16x16x32_bf16(af[i], bfr[j], acc[i][j], 0, 0, 0);
    __syncthreads();                     // next-tile loads overlapped the MFMAs
    cur ^= 1;
  }

  for (int i = 0; i < 4; ++i)
    for (int j = 0; j < NJ; ++j) {
      int row = m0 + wm * 64 + i * 16 + quad * 4;
      int col = n0 + wn * (BN / 2) + j * 16 + lq;
      float bb = bias[col];
      float sc = (col < scale_cols) ? 0.125f : 1.0f;
      for (int r = 0; r < 4; ++r) {
        float v = (acc[i][j][r] + bb) * sc;
        if (OUT_F32) ((float*)Cout)[(size_t)(row + r) * N + col] = v;
        else         ((u16*)Cout)[(size_t)(row + r) * N + col] = f2b(v);
      }
    }
}

// ---------------------------------------------------------------------------
// Flash attention (causal). 1 wave, 2 adjacent 16-query tiles, KVBLK=64.
// Split-K: heavy pairs (u>=32) split into two key-range halves writing fp32
// partials (z, m, l); light pairs unchanged. Grid 3072 (12 waves/CU). CU
// slot triple {unsplit s0, half0(63-s0), half1(63-s0)} = constant ~33 chunks.
// __launch_bounds__(64, 2): round-8's (64,4) capped VGPR at 64 -> the
// 64-reg K/V buffers spilled to scratch (FETCH 232 MB, WRITE 312 MB, 2.4x
// slower). At the natural 112 VGPR, 4 waves/SIMD fit WITHOUT the cap.
// ---------------------------------------------------------------------------
template<bool SPLIT>
__global__ __launch_bounds__(64, 2) void attn_fwd(const u16* __restrict__ QKV,
                                                  const u16* __restrict__ VT,
                                                  u16* __restrict__ Z,
                                                  float* __restrict__ Zp,
                                                  float2* __restrict__ ml) {
  __shared__ __align__(16) u16 sP[2][2][16 * 72];   // [tile][pingpong]
  const int lane = threadIdx.x;
  const int lq = lane & 15, quad = lane >> 4;

  int g, u, c_lo, c_hi, part_p;
  const int id  = blockIdx.x;
  const int xcd = id & 7;
  if (SPLIT) {
    const int slot = id >> 3;            // 0..383
    const int cwx  = slot / 96;          // combo-within-XCD 0..3
    const int rr   = slot % 96;
    const int s0   = rr & 31;
    const int role = rr >> 5;            // 0: unsplit, 1: half0, 2: half1
    g = xcd + 8 * cwx;
    if (role == 0) { u = s0; c_lo = 0; c_hi = u / 2 + 1; part_p = -1; }
    else {
      u = 63 - s0;
      const int nc = u / 2 + 1, nc0 = nc >> 1;
      part_p = role - 1;
      c_lo = part_p ? nc0 : 0;
      c_hi = part_p ? nc  : nc0;
    }
  } else {
    const int slot = id >> 3;
    g = xcd + 8 * (slot >> 6);
    const int ss = slot & 63;
    u = (ss < 32) ? (63 - ss) : (ss - 32);
    c_lo = 0; c_hi = u / 2 + 1; part_p = -1;
  }
  const int nfull = u / 2 + 1;           // true last chunk = nfull-1 (masked)
  const int h = g & 15, b = g >> 4;
  const int qA = u * 32, qB = qA + 16;

  const int RS = 3072;
  const u16* base = QKV + (size_t)b * 2048 * RS;
  const u16* Qb  = base + h * 64;
  const u16* Kb  = base + 1024 + h * 64;
  const u16* VTb = VT + (size_t)h * 64 * 4096 + (size_t)b * 2048;

  // Q frags (B-operand): lane holds Q[q+lq][d = 32*half + quad*8 + j]
  s8v qfA0 = *(const s8v*)&Qb[(size_t)(qA + lq) * RS + quad * 8];
  s8v qfA1 = *(const s8v*)&Qb[(size_t)(qA + lq) * RS + 32 + quad * 8];
  s8v qfB0 = *(const s8v*)&Qb[(size_t)(qB + lq) * RS + quad * 8];
  s8v qfB1 = *(const s8v*)&Qb[(size_t)(qB + lq) * RS + 32 + quad * 8];

  f4v zA[4] = {}, zB[4] = {};
  float mA = -3.0e38f, lA = 0.f, mB = -3.0e38f, lB = 0.f;

  s8v kf[8], vf[8];   // single buffers: K rows / V cols of the current chunk

#define LOADK(c_) do {                                                        \
    const int kk0_ = (c_) * 64;                                               \
    _Pragma("unroll")                                                         \
    for (int i_ = 0; i_ < 4; ++i_) {                                          \
      const u16* kr_ = &Kb[(size_t)(kk0_ + 16 * i_ + lq) * RS + quad * 8];    \
      kf[2 * i_]     = *(const s8v*)kr_;                                      \
      kf[2 * i_ + 1] = *(const s8v*)(kr_ + 32);                               \
    }                                                                         \
  } while (0)

#define LOADV(c_) do {                                                        \
    const int kk0_ = (c_) * 64;                                               \
    _Pragma("unroll")                                                         \
    for (int d_ = 0; d_ < 4; ++d_) {                                          \
      const u16* vr_ = &VTb[(size_t)(d_ * 16 + lq) * 4096 + kk0_ + quad * 8]; \
      vf[d_]     = *(const s8v*)vr_;                                          \
      vf[d_ + 4] = *(const s8v*)(vr_ + 32);                                   \
    }                                                                         \
  } while (0)

  // softmax of 64-key chunk c for one tile (swapped layout) + packed P write
  auto SMW = [&](int c, int qt0, float& mrow, float& lsum, f4v (&zacc)[4],
                 u16* sPt, f4v (&sc)[4]) {
    float sv[4][4];
    for (int i = 0; i < 4; ++i)
      for (int r = 0; r < 4; ++r) sv[i][r] = sc[i][r];
    if (c == nfull - 1) {               // only the true last chunk crosses diag
      const int kb = c * 64;
      for (int i = 0; i < 4; ++i)
        for (int r = 0; r < 4; ++r)
          if (kb + 16 * i + quad * 4 + r > qt0 + lq) sv[i][r] = -3.0e38f;
    }
    float lmax = sv[0][0];
    for (int i = 0; i < 4; ++i)
      for (int r = 0; r < 4; ++r) lmax = fmaxf(lmax, sv[i][r]);
    if (!__all(lmax <= mrow + 8.0f)) {  // defer-max, THR=8
      float t = lmax;
      t = fmaxf(t, __shfl_xor(t, 16, 64));
      t = fmaxf(t, __shfl_xor(t, 32, 64));
      float mnew = fmaxf(mrow, t);
      float al = __expf(mrow - mnew);
      mrow = mnew;
      lsum *= al;
      float alr[4];
      for (int r = 0; r < 4; ++r) alr[r] = __shfl(al, quad * 4 + r, 16);
      for (int dc = 0; dc < 4; ++dc)
        for (int r = 0; r < 4; ++r) zacc[dc][r] *= alr[r];
    }
    float acc = 0.f;
    float p[4][4];
    for (int i = 0; i < 4; ++i)
      for (int r = 0; r < 4; ++r) {
        p[i][r] = __expf(sv[i][r] - mrow);
        acc += p[i][r];
      }
    lsum += acc;
    for (int i = 0; i < 4; ++i) {
      uint2 w;
      w.x = pk2(p[i][0], p[i][1]);
      w.y = pk2(p[i][2], p[i][3]);
      *(uint2*)&sPt[lq * 72 + 16 * i + quad * 4] = w;
    }
  };

#define QK(aA_, aB_) do {                                                     \
    _Pragma("unroll")                                                         \
    for (int i_ = 0; i_ < 4; ++i_) {                                          \
      aA_[i_] = __builtin_amdgcn_mfma_f32_16x16x32_bf16(kf[2*i_],   qfA0, aA_[i_], 0, 0, 0); \
      aA_[i_] = __builtin_amdgcn_mfma_f32_16x16x32_bf16(kf[2*i_+1], qfA1, aA_[i_], 0, 0, 0); \
      aB_[i_] = __builtin_amdgcn_mfma_f32_16x16x32_bf16(kf[2*i_],   qfB0, aB_[i_], 0, 0, 0); \
      aB_[i_] = __builtin_amdgcn_mfma_f32_16x16x32_bf16(kf[2*i_+1], qfB1, aB_[i_], 0, 0, 0); \
    }                                                                         \
  } while (0)

  auto PV = [&](int pb) {
    s8v pA0 = *(const s8v*)&sP[0][pb][lq * 72 + quad * 8];
    s8v pA1 = *(const s8v*)&sP[0][pb][lq * 72 + 32 + quad * 8];
    s8v pB0 = *(const s8v*)&sP[1][pb][lq * 72 + quad * 8];
    s8v pB1 = *(const s8v*)&sP[1][pb][lq * 72 + 32 + quad * 8];
#pragma unroll
    for (int d_ = 0; d_ < 4; ++d_) {
      zA[d_] = __builtin_amdgcn_mfma_f32_16x16x32_bf16(pA0, vf[d_],     zA[d_], 0, 0, 0);
      zA[d_] = __builtin_amdgcn_mfma_f32_16x16x32_bf16(pA1, vf[d_ + 4], zA[d_], 0, 0, 0);
      zB[d_] = __builtin_amdgcn_mfma_f32_16x16x32_bf16(pB0, vf[d_],     zB[d_], 0, 0, 0);
      zB[d_] = __builtin_amdgcn_mfma_f32_16x16x32_bf16(pB1, vf[d_ + 4], zB[d_], 0, 0, 0);
    }
  };

  LOADK(c_lo);
  { // first chunk of range: QK + softmax + P write (PV deferred)
    f4v aA[4] = {}, aB[4] = {};
    __builtin_amdgcn_s_setprio(1);
    QK(aA, aB);
    __builtin_amdgcn_s_setprio(0);
    if (c_lo + 1 < c_hi) LOADK(c_lo + 1);
    LOADV(c_lo);
    SMW(c_lo, qA, mA, lA, zA, sP[0][c_lo & 1], aA);
    SMW(c_lo, qB, mB, lB, zB, sP[1][c_lo & 1], aB);
    asm volatile("" ::: "memory");
  }

  for (int c = c_lo + 1; c < c_hi; ++c) {
    f4v aA[4] = {}, aB[4] = {};
    __builtin_amdgcn_s_setprio(1);
    QK(aA, aB);                         // kf = K(c)
    PV((c + 1) & 1);                    // reads P(c-1) + vf = V(c-1)
    __builtin_amdgcn_s_setprio(0);
    asm volatile("" ::: "memory");
    if (c + 1 < c_hi) LOADK(c + 1);
    LOADV(c);
    SMW(c, qA, mA, lA, zA, sP[0][c & 1], aA);
    SMW(c, qB, mB, lB, zB, sP[1][c & 1], aB);
    asm volatile("" ::: "memory");
  }

  { // drain: PV of last chunk in range
    __builtin_amdgcn_s_setprio(1);
    PV((c_hi - 1) & 1);
    __builtin_amdgcn_s_setprio(0);
  }
#undef QK
#undef LOADK
#undef LOADV

  // sum reduction across the 4 quad-lanes of each row
  lA += __shfl_xor(lA, 16, 64); lA += __shfl_xor(lA, 32, 64);
  lB += __shfl_xor(lB, 16, 64); lB += __shfl_xor(lB, 32, 64);

  if (!SPLIT || part_p < 0) {           // full pair: normalize + write Z bf16
    float invA[4], invB[4];
    for (int r = 0; r < 4; ++r) {
      invA[r] = 1.0f / __shfl(lA, quad * 4 + r, 16);
      invB[r] = 1.0f / __shfl(lB, quad * 4 + r, 16);
    }
    for (int dc = 0; dc < 4; ++dc)
      for (int r = 0; r < 4; ++r) {
        size_t rowA = (size_t)b * 2048 + qA + quad * 4 + r;
        size_t rowB = (size_t)b * 2048 + qB + quad * 4 + r;
        Z[rowA * 1024 + h * 64 + dc * 16 + lq] = f2b(zA[dc][r] * invA[r]);
        Z[rowB * 1024 + h * 64 + dc * 16 + lq] = f2b(zB[dc][r] * invB[r]);
      }
  } else {                              // half pair: write fp32 partials
    float* ZpP = Zp + (size_t)part_p * (32768 * 64);
    const int prA = g * 1024 + (qA - 1024) + quad * 4;   // qA >= 1024 here
    const int prB = g * 1024 + (qB - 1024) + quad * 4;
    for (int dc = 0; dc < 4; ++dc)
      for (int r = 0; r < 4; ++r) {
        ZpP[(size_t)(prA + r) * 64 + dc * 16 + lq] = zA[dc][r];
        ZpP[(size_t)(prB + r) * 64 + dc * 16 + lq] = zB[dc][r];
      }
    if (quad == 0) {                    // lane lq owns row q0+lq's (m,l)
      ml[(size_t)part_p * 32768 + g * 1024 + (qA - 1024) + lq] = make_float2(mA, lA);
      ml[(size_t)part_p * 32768 + g * 1024 + (qB - 1024) + lq] = make_float2(mB, lB);
    }
  }
}

// ---------------------------------------------------------------------------
// Combine split-K halves for rows q in [1024, 2048) of each (b,h).
// out = (z0*w0 + z1*w1) / (l0*w0 + l1*w1), wp = exp(mp - max(m0,m1)). Exact.
// ---------------------------------------------------------------------------
__global__ void combine(const float* __restrict__ Zp, const float2* __restrict__ ml,
                        u16* __restrict__ Z) {
  const int t = blockIdx.x * 256 + threadIdx.x;     // < 524288
  const int row = t >> 4;
  const int dseg = (t & 15) * 4;
  const float2 a = ml[row];
  const float2 c = ml[32768 + row];
  const float M  = fmaxf(a.x, c.x);
  const float w0 = __expf(a.x - M), w1 = __expf(c.x - M);
  const float inv = 1.0f / (a.y * w0 + c.y * w1);
  const float4 z0 = *(const float4*)&Zp[(size_t)row * 64 + dseg];
  const float4 z1 = *(const float4*)&Zp[(size_t)32768 * 64 + (size_t)row * 64 + dseg];
  const float o0 = (z0.x * w0 + z1.x * w1) * inv;
  const float o1 = (z0.y * w0 + z1.y * w1) * inv;
  const float o2 = (z0.z * w0 + z1.z * w1) * inv;
  const float o3 = (z0.w * w0 + z1.w * w1) * inv;
  const int g = row >> 10, qloc = row & 1023;
  const int bb = g >> 4, hh = g & 15;
  const size_t zoff = ((size_t)bb * 2048 + 1024 + qloc) * 1024 + hh * 64 + dseg;
  uint2 w;
  w.x = pk2(o0, o1);
  w.y = pk2(o2, o3);
  *(uint2*)&Z[zoff] = w;
}

// ---------------------------------------------------------------------------
// Launch
// ---------------------------------------------------------------------------
extern "C" void kernel_launch(void* const* d_in, const int* in_sizes, int n_in,
                              void* d_out, int out_size, void* d_ws, size_t ws_size,
                              hipStream_t stream) {
  const float* x  = (const float*)d_in[0];
  const float* WQ = (const float*)d_in[1];
  const float* bQ = (const float*)d_in[2];
  const float* WK = (const float*)d_in[3];
  const float* bK = (const float*)d_in[4];
  const float* WV = (const float*)d_in[5];
  const float* WO = (const float*)d_in[6];
  const float* bV = (const float*)d_in[7];
  const float* bO = (const float*)d_in[8];
  float* out = (float*)d_out;

  uint8_t* ws = (uint8_t*)d_ws;
  u16*   xb    = (u16*)(ws);                       //  8 MB  (dead after QKV GEMM)
  u16*   VTv   = (u16*)(ws);                       //  8 MB  V^T (reuses xb)
  u16*   WTqkv = (u16*)(ws + 8388608);             //  6 MB
  u16*   WOT   = (u16*)(ws + 14680064);            //  2 MB
  u16*   QKV   = (u16*)(ws + 16777216);            // 24 MB
  u16*   Zb    = (u16*)(ws + 41943040);            //  8 MB
  float* bqkv  = (float*)(ws + 50331648);          // 12 KB
  float* bsum  = (float*)(ws + 50343936);          //  4 KB
  float* Zp    = (float*)(ws + 50348032);          // 16 MB  split-K partials
  float2* mlp  = (float2*)(ws + 67125248);         // 512 KB (m,l) per partial row
  const bool do_split = ws_size >= 67649536ull;    // host-static; fallback if small

  // fused prep: conv_x + 3x convT_w + convT_wo + conv_bias
  prep<<<5136, 256, 0, stream>>>(x, xb, WQ, WK, WV, WO, WTqkv, WOT,
                                 bQ, bK, bV, bO, bqkv, bsum);
  // QKV projection: Q columns pre-scaled by 0.125 (exact in bf16)
  gemm_bt<false, 128><<<dim3(24, 32), 256, 0, stream>>>(xb, WTqkv, bqkv, (void*)QKV, 3072, 1024, 1024);
  // V transpose (xb dead; VT reuses its workspace)
  convT_v<<<dim3(64, 16), 256, 0, stream>>>(QKV, VTv);
  // attention
  if (do_split) {
    attn_fwd<true><<<dim3(3072, 1, 1), 64, 0, stream>>>(QKV, VTv, Zb, Zp, mlp);
    combine<<<2048, 256, 0, stream>>>(Zp, mlp, Zb);
  } else {
    attn_fwd<false><<<dim3(2048, 1, 1), 64, 0, stream>>>(QKV, VTv, Zb, Zp, mlp);
  }
  // output projection: [4096x1024] x [1024x1024] -> fp32 out (+ sum_h b_O)
  gemm_bt<true, 64><<<dim3(16, 32), 256, 0, stream>>>(Zb, WOT, bsum, (void*)out, 1024, 1024, 0);
}

// Round 11
// 220.650 us; speedup vs baseline: 1.4998x; 1.0698x over previous
//
#include <hip/hip_runtime.h>
#include <cstdint>

typedef unsigned short u16;
typedef short s8v __attribute__((ext_vector_type(8)));
typedef float f4v __attribute__((ext_vector_type(4)));

// fp32 -> bf16 round-to-nearest-even (bit trick)
__device__ __forceinline__ u16 f2b(float f) {
  uint32_t u = __float_as_uint(f);
  u = (u + 0x7FFFu + ((u >> 16) & 1u)) >> 16;
  return (u16)u;
}

// pack two f32 -> bf16x2 (RNE) in one instruction (T12 recipe; no builtin)
__device__ __forceinline__ uint32_t pk2(float a, float b) {
  uint32_t r;
  asm("v_cvt_pk_bf16_f32 %0, %1, %2" : "=v"(r) : "v"(a), "v"(b));
  return r;
}

// async global->LDS, 16B per lane (wave-uniform LDS base + lane*16 layout)
__device__ __forceinline__ void gload16(const u16* g, u16* l) {
  __builtin_amdgcn_global_load_lds(
      (const __attribute__((address_space(1))) void*)g,
      (__attribute__((address_space(3))) void*)l, 16, 0, 0);
}

// ---------------------------------------------------------------------------
// Fused prep kernel
// blocks: [0,4096) conv_x | [4096,4864) convT_w | [4864,5120) convT_wo |
//         [5120,5136) conv_bias
// ---------------------------------------------------------------------------
__global__ void prep(const float* __restrict__ x, u16* __restrict__ xb,
                     const float* __restrict__ WQ, const float* __restrict__ WK,
                     const float* __restrict__ WV, const float* __restrict__ WO,
                     u16* __restrict__ WTqkv, u16* __restrict__ WOT,
                     const float* __restrict__ bQ, const float* __restrict__ bK,
                     const float* __restrict__ bV, const float* __restrict__ bO,
                     float* __restrict__ bqkv, float* __restrict__ bsum) {
  __shared__ u16 tile[64][65];
  const int bid = blockIdx.x;
  const int tid = threadIdx.x;

  if (bid < 4096) {                       // x fp32 -> bf16, 4 elems/thread
    int i = bid * 256 + tid;
    float4 v = ((const float4*)x)[i];
    uint2 o;
    o.x = (uint32_t)f2b(v.x) | ((uint32_t)f2b(v.y) << 16);
    o.y = (uint32_t)f2b(v.z) | ((uint32_t)f2b(v.w) << 16);
    ((uint2*)xb)[i] = o;
  } else if (bid < 4864) {                // W_{Q,K,V} -> WTqkv (B^T), 64x64 transpose
    int sub = bid - 4096;
    int w = sub >> 8, sub2 = sub & 255;
    const float* W = (w == 0) ? WQ : (w == 1) ? WK : WV;
    u16* dst = WTqkv + (size_t)w * 1024 * 1024;
    const int m0 = (sub2 & 15) * 64;
    const int h  = sub2 >> 4;
    const int c  = tid & 63;
    const int r4 = tid >> 6;
    const float* Wh = W + (size_t)h * 65536;
    for (int i = 0; i < 16; ++i) {
      int lm = i * 4 + r4;
      tile[lm][c] = f2b(Wh[(size_t)(m0 + lm) * 64 + c]);
    }
    __syncthreads();
    for (int i = 0; i < 16; ++i) {
      int dd = i * 4 + r4;
      dst[((size_t)h * 64 + dd) * 1024 + m0 + c] = tile[c][dd];
    }
  } else if (bid < 5120) {                // W_O flat [1024][1024] -> WOT[m][k]
    int sub = bid - 4864;
    const int k0 = (sub & 15) * 64;
    const int m0 = (sub >> 4) * 64;
    const int c  = tid & 63;
    const int r4 = tid >> 6;
    for (int i = 0; i < 16; ++i) {
      int lk = i * 4 + r4;
      tile[lk][c] = f2b(WO[(size_t)(k0 + lk) * 1024 + m0 + c]);
    }
    __syncthreads();
    for (int i = 0; i < 16; ++i) {
      int lm = i * 4 + r4;
      WOT[(size_t)(m0 + lm) * 1024 + k0 + c] = tile[c][lm];
    }
  } else {                                // biases
    int t = (bid - 5120) * 256 + tid;
    if (t < 1024)       bqkv[t] = bQ[t];
    else if (t < 2048)  bqkv[t] = bK[t - 1024];
    else if (t < 3072)  bqkv[t] = bV[t - 2048];
    else {
      int m = t - 3072;
      float s = 0.f;
      for (int hh = 0; hh < 16; ++hh) s += bO[hh * 1024 + m];
      bsum[m] = s;
    }
  }
}

// V columns of QKV [4096][3072] (cols 2048..3071) -> VT[(h*64+d)][token] bf16.
__global__ void convT_v(const u16* __restrict__ QKV, u16* __restrict__ VT) {
  __shared__ u16 tile[64][65];
  const int r0 = blockIdx.x * 64;
  const int c0 = blockIdx.y * 64;
  const int c  = threadIdx.x & 63;
  const int r4 = threadIdx.x >> 6;
  for (int i = 0; i < 16; ++i) {
    int lr = i * 4 + r4;
    tile[lr][c] = QKV[(size_t)(r0 + lr) * 3072 + 2048 + c0 + c];
  }
  __syncthreads();
  for (int i = 0; i < 16; ++i) {
    int lc = i * 4 + r4;
    VT[(size_t)(c0 + lc) * 4096 + r0 + c] = tile[c][lc];
  }
}

// ---------------------------------------------------------------------------
// bf16 MFMA GEMM: C = (A * BT^T + bias[col]) * (col<scale_cols ? 0.125 : 1)
// Generalized BMxBN tile, BK=32, NTHR/64 waves arranged (NW/2) x 2; each wave
// owns a 64x(BN/2) sub-tile with the PROVEN per-wave fragment geometry
// (M_rep=4, N_rep=BN/32). 2-phase pipeline: double-buffered LDS, STAGE(next)
// issued BEFORE ds_read+MFMA of current, one barrier per K-step.
//   QKV proj:  BM=256, BN=128, 512 thr (8 waves 4x2)  -> 384 blocks, LDS 48KB
//   out proj:  BM=128, BN=64,  256 thr (4 waves 2x2)  -> 512 blocks
// Bigger BM halves per-FLOP global traffic (A shared by 2 wave-cols, B by 4
// wave-rows) at identical per-wave MFMA density.
// ---------------------------------------------------------------------------
template<bool OUT_F32, int BM, int BN, int NTHR>
__global__ void gemm_bt(const u16* __restrict__ A, const u16* __restrict__ BT,
                        const float* __restrict__ bias, void* __restrict__ Cout,
                        int N, int K, int scale_cols) {
  constexpr int NW = NTHR / 64;          // waves
  constexpr int WM = NW / 2;             // wave rows (wave grid WM x 2)
  constexpr int NJ = BN / 32;            // N_rep per wave (cols = NJ*16)
  static_assert(BM / WM == 64, "per-wave rows must be 64");
  static_assert(BM * 4 == 2 * NTHR, "A staging: 2 segs/thread");
  static_assert(BN * 4 == NTHR, "B staging: 1 seg/thread");

  __shared__ __align__(16) u16 sA[2][BM * 32];
  __shared__ __align__(16) u16 sB[2][BN * 32];
  const int tid  = threadIdx.x;
  const int lane = tid & 63, wave = tid >> 6;
  const int wm = wave >> 1, wn = wave & 1;
  const int lq = lane & 15, quad = lane >> 4;
  const int m0 = blockIdx.y * BM, n0 = blockIdx.x * BN;

  f4v acc[4][NJ] = {};

  auto STAGE = [&](int buf, int k0) {
    for (int i = 0; i < 2; ++i) {        // A tile BMx32: 2 segs/thread
      int s = tid + i * NTHR;
      int row = s >> 2, part = s & 3;
      gload16(A + (size_t)(m0 + row) * K + k0 + part * 8, &sA[buf][s * 8]);
    }
    {                                    // B tile BNx32: 1 seg/thread
      int row = tid >> 2, part = tid & 3;
      gload16(BT + (size_t)(n0 + row) * K + k0 + part * 8, &sB[buf][tid * 8]);
    }
  };

  STAGE(0, 0);
  __syncthreads();                       // compiler drains vmcnt before barrier
  int cur = 0;
  for (int k0 = 0; k0 < K; k0 += 32) {
    if (k0 + 32 < K) STAGE(cur ^ 1, k0 + 32);   // issue next-tile loads FIRST
    s8v af[4], bfr[NJ];
    for (int i = 0; i < 4; ++i)
      af[i]  = *(const s8v*)&sA[cur][(wm * 64 + i * 16 + lq) * 32 + quad * 8];
    for (int j = 0; j < NJ; ++j)
      bfr[j] = *(const s8v*)&sB[cur][(wn * (BN / 2) + j * 16 + lq) * 32 + quad * 8];
    for (int i = 0; i < 4; ++i)
      for (int j = 0; j < NJ; ++j)
        acc[i][j] = __builtin_amdgcn_mfma_f32_16x16x32_bf16(af[i], bfr[j], acc[i][j], 0, 0, 0);
    __syncthreads();                     // next-tile loads overlapped the MFMAs
    cur ^= 1;
  }

  for (int i = 0; i < 4; ++i)
    for (int j = 0; j < NJ; ++j) {
      int row = m0 + wm * 64 + i * 16 + quad * 4;
      int col = n0 + wn * (BN / 2) + j * 16 + lq;
      float bb = bias[col];
      float sc = (col < scale_cols) ? 0.125f : 1.0f;
      for (int r = 0; r < 4; ++r) {
        float v = (acc[i][j][r] + bb) * sc;
        if (OUT_F32) ((float*)Cout)[(size_t)(row + r) * N + col] = v;
        else         ((u16*)Cout)[(size_t)(row + r) * N + col] = f2b(v);
      }
    }
}

// ---------------------------------------------------------------------------
// Flash attention (causal). 1 wave, 2 adjacent 16-query tiles, KVBLK=64.
// Round-7 structure (best measured: 71us). Heavy+light CU pairing, single
// K/V register buffers reloaded after MFMA consumption, ping-pong P LDS
// with compiler fences, setprio around MFMA clusters.
// ---------------------------------------------------------------------------
__global__ __launch_bounds__(64, 2) void attn_fwd(const u16* __restrict__ QKV,
                                                  const u16* __restrict__ VT,
                                                  u16* __restrict__ Z) {
  __shared__ __align__(16) u16 sP[2][2][16 * 72];   // [tile][pingpong]
  const int lane = threadIdx.x;
  const int lq = lane & 15, quad = lane >> 4;

  const int id   = blockIdx.x;             // 0..2047
  const int xcd  = id & 7;
  const int slot = id >> 3;                // 0..255 per XCD
  const int g    = xcd + 8 * (slot >> 6);  // combo 0..31
  const int s    = slot & 63;
  const int u    = (s < 32) ? (63 - s) : (s - 32);  // heavy+light pairing
  const int h = g & 15, b = g >> 4;
  const int qA = u * 32, qB = qA + 16;
  const int nchunk = u / 2 + 1;            // 64-key chunks

  const int RS = 3072;
  const u16* base = QKV + (size_t)b * 2048 * RS;
  const u16* Qb  = base + h * 64;
  const u16* Kb  = base + 1024 + h * 64;
  const u16* VTb = VT + (size_t)h * 64 * 4096 + (size_t)b * 2048;

  // Q frags (B-operand): lane holds Q[q+lq][d = 32*half + quad*8 + j]
  s8v qfA0 = *(const s8v*)&Qb[(size_t)(qA + lq) * RS + quad * 8];
  s8v qfA1 = *(const s8v*)&Qb[(size_t)(qA + lq) * RS + 32 + quad * 8];
  s8v qfB0 = *(const s8v*)&Qb[(size_t)(qB + lq) * RS + quad * 8];
  s8v qfB1 = *(const s8v*)&Qb[(size_t)(qB + lq) * RS + 32 + quad * 8];

  f4v zA[4] = {}, zB[4] = {};
  float mA = -3.0e38f, lA = 0.f, mB = -3.0e38f, lB = 0.f;

  s8v kf[8], vf[8];   // single buffers: K rows / V cols of the current chunk

#define LOADK(c_) do {                                                        \
    const int kk0_ = (c_) * 64;                                               \
    _Pragma("unroll")                                                         \
    for (int i_ = 0; i_ < 4; ++i_) {                                          \
      const u16* kr_ = &Kb[(size_t)(kk0_ + 16 * i_ + lq) * RS + quad * 8];    \
      kf[2 * i_]     = *(const s8v*)kr_;                                      \
      kf[2 * i_ + 1] = *(const s8v*)(kr_ + 32);                               \
    }                                                                         \
  } while (0)

#define LOADV(c_) do {                                                        \
    const int kk0_ = (c_) * 64;                                               \
    _Pragma("unroll")                                                         \
    for (int d_ = 0; d_ < 4; ++d_) {                                          \
      const u16* vr_ = &VTb[(size_t)(d_ * 16 + lq) * 4096 + kk0_ + quad * 8]; \
      vf[d_]     = *(const s8v*)vr_;                                          \
      vf[d_ + 4] = *(const s8v*)(vr_ + 32);                                   \
    }                                                                         \
  } while (0)

  // softmax of 64-key chunk c for one tile (swapped layout) + packed P write
  auto SMW = [&](int c, int qt0, float& mrow, float& lsum, f4v (&zacc)[4],
                 u16* sPt, f4v (&sc)[4]) {
    float sv[4][4];
    for (int i = 0; i < 4; ++i)
      for (int r = 0; r < 4; ++r) sv[i][r] = sc[i][r];
    if (c + 1 == nchunk) {              // only the last chunk crosses the diagonal
      const int kb = c * 64;
      for (int i = 0; i < 4; ++i)
        for (int r = 0; r < 4; ++r)
          if (kb + 16 * i + quad * 4 + r > qt0 + lq) sv[i][r] = -3.0e38f;
    }
    float lmax = sv[0][0];
    for (int i = 0; i < 4; ++i)
      for (int r = 0; r < 4; ++r) lmax = fmaxf(lmax, sv[i][r]);
    if (!__all(lmax <= mrow + 8.0f)) {  // defer-max, THR=8
      float t = lmax;
      t = fmaxf(t, __shfl_xor(t, 16, 64));
      t = fmaxf(t, __shfl_xor(t, 32, 64));
      float mnew = fmaxf(mrow, t);
      float al = __expf(mrow - mnew);
      mrow = mnew;
      lsum *= al;
      float alr[4];
      for (int r = 0; r < 4; ++r) alr[r] = __shfl(al, quad * 4 + r, 16);
      for (int dc = 0; dc < 4; ++dc)
        for (int r = 0; r < 4; ++r) zacc[dc][r] *= alr[r];
    }
    float acc = 0.f;
    float p[4][4];
    for (int i = 0; i < 4; ++i)
      for (int r = 0; r < 4; ++r) {
        p[i][r] = __expf(sv[i][r] - mrow);
        acc += p[i][r];
      }
    lsum += acc;
    for (int i = 0; i < 4; ++i) {
      uint2 w;
      w.x = pk2(p[i][0], p[i][1]);
      w.y = pk2(p[i][2], p[i][3]);
      *(uint2*)&sPt[lq * 72 + 16 * i + quad * 4] = w;
    }
  };

#define QK(aA_, aB_) do {                                                     \
    _Pragma("unroll")                                                         \
    for (int i_ = 0; i_ < 4; ++i_) {                                          \
      aA_[i_] = __builtin_amdgcn_mfma_f32_16x16x32_bf16(kf[2*i_],   qfA0, aA_[i_], 0, 0, 0); \
      aA_[i_] = __builtin_amdgcn_mfma_f32_16x16x32_bf16(kf[2*i_+1], qfA1, aA_[i_], 0, 0, 0); \
      aB_[i_] = __builtin_amdgcn_mfma_f32_16x16x32_bf16(kf[2*i_],   qfB0, aB_[i_], 0, 0, 0); \
      aB_[i_] = __builtin_amdgcn_mfma_f32_16x16x32_bf16(kf[2*i_+1], qfB1, aB_[i_], 0, 0, 0); \
    }                                                                         \
  } while (0)

  // PV from ping-pong buffer pb (P of the previous chunk) + current vf
  auto PV = [&](int pb) {
    s8v pA0 = *(const s8v*)&sP[0][pb][lq * 72 + quad * 8];
    s8v pA1 = *(const s8v*)&sP[0][pb][lq * 72 + 32 + quad * 8];
    s8v pB0 = *(const s8v*)&sP[1][pb][lq * 72 + quad * 8];
    s8v pB1 = *(const s8v*)&sP[1][pb][lq * 72 + 32 + quad * 8];
#pragma unroll
    for (int d_ = 0; d_ < 4; ++d_) {
      zA[d_] = __builtin_amdgcn_mfma_f32_16x16x32_bf16(pA0, vf[d_],     zA[d_], 0, 0, 0);
      zA[d_] = __builtin_amdgcn_mfma_f32_16x16x32_bf16(pA1, vf[d_ + 4], zA[d_], 0, 0, 0);
      zB[d_] = __builtin_amdgcn_mfma_f32_16x16x32_bf16(pB0, vf[d_],     zB[d_], 0, 0, 0);
      zB[d_] = __builtin_amdgcn_mfma_f32_16x16x32_bf16(pB1, vf[d_ + 4], zB[d_], 0, 0, 0);
    }
  };

  LOADK(0);
  { // chunk 0: QK + softmax + P write into buf 0 (PV deferred)
    f4v aA[4] = {}, aB[4] = {};
    __builtin_amdgcn_s_setprio(1);
    QK(aA, aB);
    __builtin_amdgcn_s_setprio(0);
    if (nchunk > 1) LOADK(1);
    LOADV(0);
    SMW(0, qA, mA, lA, zA, sP[0][0], aA);
    SMW(0, qB, mB, lB, zB, sP[1][0], aB);
    asm volatile("" ::: "memory");      // P(0) writes pinned before PV reads
  }

  for (int c = 1; c < nchunk; ++c) {
    f4v aA[4] = {}, aB[4] = {};
    __builtin_amdgcn_s_setprio(1);
    QK(aA, aB);                         // kf = K(c)
    PV((c + 1) & 1);                    // reads P(c-1) + vf = V(c-1)
    __builtin_amdgcn_s_setprio(0);
    asm volatile("" ::: "memory");      // PV reads pinned before SMW writes
    if (c + 1 < nchunk) LOADK(c + 1);   // safe: QK consumed kf at issue
    LOADV(c);                           // safe: PV consumed vf at issue
    SMW(c, qA, mA, lA, zA, sP[0][c & 1], aA);
    SMW(c, qB, mB, lB, zB, sP[1][c & 1], aB);
    asm volatile("" ::: "memory");      // P(c) writes pinned before next PV
  }

  { // drain: PV(nchunk-1) from the last-written buffer
    __builtin_amdgcn_s_setprio(1);
    PV((nchunk - 1) & 1);
    __builtin_amdgcn_s_setprio(0);
  }
#undef QK
#undef LOADK
#undef LOADV

  // one-time sum reduction across the 4 quad-lanes of each row
  lA += __shfl_xor(lA, 16, 64); lA += __shfl_xor(lA, 32, 64);
  lB += __shfl_xor(lB, 16, 64); lB += __shfl_xor(lB, 32, 64);
  float invA[4], invB[4];
  for (int r = 0; r < 4; ++r) {
    invA[r] = 1.0f / __shfl(lA, quad * 4 + r, 16);
    invB[r] = 1.0f / __shfl(lB, quad * 4 + r, 16);
  }
  for (int dc = 0; dc < 4; ++dc)
    for (int r = 0; r < 4; ++r) {
      size_t rowA = (size_t)b * 2048 + qA + quad * 4 + r;
      size_t rowB = (size_t)b * 2048 + qB + quad * 4 + r;
      Z[rowA * 1024 + h * 64 + dc * 16 + lq] = f2b(zA[dc][r] * invA[r]);
      Z[rowB * 1024 + h * 64 + dc * 16 + lq] = f2b(zB[dc][r] * invB[r]);
    }
}

// ---------------------------------------------------------------------------
// Launch
// ---------------------------------------------------------------------------
extern "C" void kernel_launch(void* const* d_in, const int* in_sizes, int n_in,
                              void* d_out, int out_size, void* d_ws, size_t ws_size,
                              hipStream_t stream) {
  const float* x  = (const float*)d_in[0];
  const float* WQ = (const float*)d_in[1];
  const float* bQ = (const float*)d_in[2];
  const float* WK = (const float*)d_in[3];
  const float* bK = (const float*)d_in[4];
  const float* WV = (const float*)d_in[5];
  const float* WO = (const float*)d_in[6];
  const float* bV = (const float*)d_in[7];
  const float* bO = (const float*)d_in[8];
  float* out = (float*)d_out;

  uint8_t* ws = (uint8_t*)d_ws;
  u16*   xb    = (u16*)(ws);                       //  8 MB  (dead after QKV GEMM)
  u16*   VTv   = (u16*)(ws);                       //  8 MB  V^T (reuses xb)
  u16*   WTqkv = (u16*)(ws + 8388608);             //  6 MB
  u16*   WOT   = (u16*)(ws + 14680064);            //  2 MB
  u16*   QKV   = (u16*)(ws + 16777216);            // 24 MB
  u16*   Zb    = (u16*)(ws + 41943040);            //  8 MB
  float* bqkv  = (float*)(ws + 50331648);          // 12 KB
  float* bsum  = (float*)(ws + 50343936);          //  4 KB

  // fused prep: conv_x + 3x convT_w + convT_wo + conv_bias
  prep<<<5136, 256, 0, stream>>>(x, xb, WQ, WK, WV, WO, WTqkv, WOT,
                                 bQ, bK, bV, bO, bqkv, bsum);
  // QKV projection (Q cols pre-scaled by 0.125): 256x128 tile, 8 waves
  gemm_bt<false, 256, 128, 512><<<dim3(24, 16), 512, 0, stream>>>(
      xb, WTqkv, bqkv, (void*)QKV, 3072, 1024, 1024);
  // V transpose (xb dead; VT reuses its workspace)
  convT_v<<<dim3(64, 16), 256, 0, stream>>>(QKV, VTv);
  // attention: round-7 proven config, 2048 one-wave blocks
  attn_fwd<<<dim3(2048, 1, 1), 64, 0, stream>>>(QKV, VTv, Zb);
  // output projection: 128x64 tile, 4 waves, 512 blocks
  gemm_bt<true, 128, 64, 256><<<dim3(16, 32), 256, 0, stream>>>(
      Zb, WOT, bsum, (void*)out, 1024, 1024, 0);
}

// Round 12
// 209.691 us; speedup vs baseline: 1.5782x; 1.0523x over previous
//
#include <hip/hip_runtime.h>
#include <cstdint>

typedef unsigned short u16;
typedef short s8v __attribute__((ext_vector_type(8)));
typedef float f4v __attribute__((ext_vector_type(4)));

// fp32 -> bf16 round-to-nearest-even (bit trick)
__device__ __forceinline__ u16 f2b(float f) {
  uint32_t u = __float_as_uint(f);
  u = (u + 0x7FFFu + ((u >> 16) & 1u)) >> 16;
  return (u16)u;
}

// pack two f32 -> bf16x2 (RNE) in one instruction (T12 recipe; no builtin)
__device__ __forceinline__ uint32_t pk2(float a, float b) {
  uint32_t r;
  asm("v_cvt_pk_bf16_f32 %0, %1, %2" : "=v"(r) : "v"(a), "v"(b));
  return r;
}

// async global->LDS, 16B per lane (wave-uniform LDS base + lane*16 layout)
__device__ __forceinline__ void gload16(const u16* g, u16* l) {
  __builtin_amdgcn_global_load_lds(
      (const __attribute__((address_space(1))) void*)g,
      (__attribute__((address_space(3))) void*)l, 16, 0, 0);
}

// ---------------------------------------------------------------------------
// Fused prep kernel
// blocks: [0,4096) conv_x | [4096,4864) convT_w | [4864,5120) convT_wo |
//         [5120,5136) conv_bias
// ---------------------------------------------------------------------------
__global__ void prep(const float* __restrict__ x, u16* __restrict__ xb,
                     const float* __restrict__ WQ, const float* __restrict__ WK,
                     const float* __restrict__ WV, const float* __restrict__ WO,
                     u16* __restrict__ WTqkv, u16* __restrict__ WOT,
                     const float* __restrict__ bQ, const float* __restrict__ bK,
                     const float* __restrict__ bV, const float* __restrict__ bO,
                     float* __restrict__ bqkv, float* __restrict__ bsum) {
  __shared__ u16 tile[64][65];
  const int bid = blockIdx.x;
  const int tid = threadIdx.x;

  if (bid < 4096) {                       // x fp32 -> bf16, 4 elems/thread
    int i = bid * 256 + tid;
    float4 v = ((const float4*)x)[i];
    uint2 o;
    o.x = (uint32_t)f2b(v.x) | ((uint32_t)f2b(v.y) << 16);
    o.y = (uint32_t)f2b(v.z) | ((uint32_t)f2b(v.w) << 16);
    ((uint2*)xb)[i] = o;
  } else if (bid < 4864) {                // W_{Q,K,V} -> WTqkv (B^T), 64x64 transpose
    int sub = bid - 4096;
    int w = sub >> 8, sub2 = sub & 255;
    const float* W = (w == 0) ? WQ : (w == 1) ? WK : WV;
    u16* dst = WTqkv + (size_t)w * 1024 * 1024;
    const int m0 = (sub2 & 15) * 64;
    const int h  = sub2 >> 4;
    const int c  = tid & 63;
    const int r4 = tid >> 6;
    const float* Wh = W + (size_t)h * 65536;
    for (int i = 0; i < 16; ++i) {
      int lm = i * 4 + r4;
      tile[lm][c] = f2b(Wh[(size_t)(m0 + lm) * 64 + c]);
    }
    __syncthreads();
    for (int i = 0; i < 16; ++i) {
      int dd = i * 4 + r4;
      dst[((size_t)h * 64 + dd) * 1024 + m0 + c] = tile[c][dd];
    }
  } else if (bid < 5120) {                // W_O flat [1024][1024] -> WOT[m][k]
    int sub = bid - 4864;
    const int k0 = (sub & 15) * 64;
    const int m0 = (sub >> 4) * 64;
    const int c  = tid & 63;
    const int r4 = tid >> 6;
    for (int i = 0; i < 16; ++i) {
      int lk = i * 4 + r4;
      tile[lk][c] = f2b(WO[(size_t)(k0 + lk) * 1024 + m0 + c]);
    }
    __syncthreads();
    for (int i = 0; i < 16; ++i) {
      int lm = i * 4 + r4;
      WOT[(size_t)(m0 + lm) * 1024 + k0 + c] = tile[c][lm];
    }
  } else {                                // biases
    int t = (bid - 5120) * 256 + tid;
    if (t < 1024)       bqkv[t] = bQ[t];
    else if (t < 2048)  bqkv[t] = bK[t - 1024];
    else if (t < 3072)  bqkv[t] = bV[t - 2048];
    else {
      int m = t - 3072;
      float s = 0.f;
      for (int hh = 0; hh < 16; ++hh) s += bO[hh * 1024 + m];
      bsum[m] = s;
    }
  }
}

// ---------------------------------------------------------------------------
// bf16 MFMA GEMM: C = (A * BT^T + bias[col]) * (col<scale_cols ? 0.125 : 1)
// BMxBN tile, BK=32, NTHR/64 waves (grid (NW/2) x 2), per-wave 64x(BN/2).
// 2-phase pipeline: double-buffered LDS, STAGE(next) before ds_read+MFMA of
// current, one barrier per K-step.
//
// FUSE_VT (QKV projection only): blocks with n0 >= 2048 compute the V columns
// and write them TRANSPOSED to VTout[(h*64+d)][token] instead of QKV:
//   C-fragments -> LDS ct[col][row] (stride 136: 16B-aligned, 2-way banks)
//   -> cooperative coalesced write (256B runs). Replaces the convT_v kernel
//   (saves 8MB QKV V-write + 16MB transpose r/w + one launch).
//
// Grid note: 128x128 -> 768 blocks = exactly 3/CU (even). Round-11's 256x128
// gave 384 = 1.5/CU -> half the CUs ran 2 serial blocks (uneven, no win).
// ---------------------------------------------------------------------------
template<bool OUT_F32, int BM, int BN, int NTHR, bool FUSE_VT>
__global__ void gemm_bt(const u16* __restrict__ A, const u16* __restrict__ BT,
                        const float* __restrict__ bias, void* __restrict__ Cout,
                        u16* __restrict__ VTout, int N, int K, int scale_cols) {
  constexpr int NW = NTHR / 64;
  constexpr int WM = NW / 2;
  constexpr int NJ = BN / 32;
  constexpr int ASEG = BM * 4 / NTHR;    // A staging segs/thread
  constexpr int BSEG = BN * 4 / NTHR;    // B staging segs/thread
  constexpr int STG_U16 = (BM + BN) * 64;          // 2 bufs * (BM+BN)*32
  constexpr int CT_STRIDE = BM + 8;                // 136 for BM=128
  constexpr int SMEM_U16 = (FUSE_VT && BN * CT_STRIDE > STG_U16)
                               ? BN * CT_STRIDE : STG_U16;
  static_assert(BM / WM == 64, "per-wave rows must be 64");
  static_assert(BM * 4 % NTHR == 0 && BN * 4 % NTHR == 0, "staging divisibility");

  __shared__ __align__(16) u16 smem[SMEM_U16];
  u16* sA = smem;                        // [2][BM*32]
  u16* sB = smem + 2 * BM * 32;          // [2][BN*32]

  const int tid  = threadIdx.x;
  const int lane = tid & 63, wave = tid >> 6;
  const int wm = wave >> 1, wn = wave & 1;
  const int lq = lane & 15, quad = lane >> 4;
  const int m0 = blockIdx.y * BM, n0 = blockIdx.x * BN;

  f4v acc[4][NJ] = {};

  auto STAGE = [&](int buf, int k0) {
    for (int i = 0; i < ASEG; ++i) {
      int s = tid + i * NTHR;
      int row = s >> 2, part = s & 3;
      gload16(A + (size_t)(m0 + row) * K + k0 + part * 8,
              &sA[buf * BM * 32 + s * 8]);
    }
    for (int i = 0; i < BSEG; ++i) {
      int s = tid + i * NTHR;
      int row = s >> 2, part = s & 3;
      gload16(BT + (size_t)(n0 + row) * K + k0 + part * 8,
              &sB[buf * BN * 32 + s * 8]);
    }
  };

  STAGE(0, 0);
  __syncthreads();                       // compiler drains vmcnt before barrier
  int cur = 0;
  for (int k0 = 0; k0 < K; k0 += 32) {
    if (k0 + 32 < K) STAGE(cur ^ 1, k0 + 32);   // issue next-tile loads FIRST
    s8v af[4], bfr[NJ];
    for (int i = 0; i < 4; ++i)
      af[i]  = *(const s8v*)&sA[cur * BM * 32 + (wm * 64 + i * 16 + lq) * 32 + quad * 8];
    for (int j = 0; j < NJ; ++j)
      bfr[j] = *(const s8v*)&sB[cur * BN * 32 + (wn * (BN / 2) + j * 16 + lq) * 32 + quad * 8];
    for (int i = 0; i < 4; ++i)
      for (int j = 0; j < NJ; ++j)
        acc[i][j] = __builtin_amdgcn_mfma_f32_16x16x32_bf16(af[i], bfr[j], acc[i][j], 0, 0, 0);
    __syncthreads();                     // next-tile loads overlapped the MFMAs
    cur ^= 1;
  }

  if (FUSE_VT && n0 >= 2048) {
    // V columns: emit transposed to VTout[(vcol)][token] via LDS.
    const int vcol0 = n0 - 2048;
    u16* ct = smem;                      // staging LDS is dead past final barrier
    for (int i = 0; i < 4; ++i)
      for (int j = 0; j < NJ; ++j) {
        int row = wm * 64 + i * 16 + quad * 4;
        int col = wn * (BN / 2) + j * 16 + lq;
        float bb = bias[n0 + col];       // V cols: no 0.125 scale
        uint2 w;
        w.x = pk2(acc[i][j][0] + bb, acc[i][j][1] + bb);
        w.y = pk2(acc[i][j][2] + bb, acc[i][j][3] + bb);
        *(uint2*)&ct[col * CT_STRIDE + row] = w;   // ds_write_b64, 8B-aligned
      }
    __syncthreads();
    // cooperative write: thread t -> col cc = t>>1, half = t&1 (BM=128: 64 u16)
    if (tid < BN * 2) {
      int cc = tid >> 1, half = tid & 1;
      const uint4* src = (const uint4*)&ct[cc * CT_STRIDE + half * (BM / 2)];
      uint4* dst = (uint4*)&VTout[(size_t)(vcol0 + cc) * 4096 + m0 + half * (BM / 2)];
#pragma unroll
      for (int k = 0; k < BM / 16; ++k) dst[k] = src[k];
    }
    return;
  }

  for (int i = 0; i < 4; ++i)
    for (int j = 0; j < NJ; ++j) {
      int row = m0 + wm * 64 + i * 16 + quad * 4;
      int col = n0 + wn * (BN / 2) + j * 16 + lq;
      float bb = bias[col];
      float sc = (col < scale_cols) ? 0.125f : 1.0f;
      for (int r = 0; r < 4; ++r) {
        float v = (acc[i][j][r] + bb) * sc;
        if (OUT_F32) ((float*)Cout)[(size_t)(row + r) * N + col] = v;
        else         ((u16*)Cout)[(size_t)(row + r) * N + col] = f2b(v);
      }
    }
}

// ---------------------------------------------------------------------------
// Flash attention (causal). 1 wave, 2 adjacent 16-query tiles, KVBLK=64.
// Round-7 structure (best measured: 71us). Heavy+light CU pairing, single
// K/V register buffers reloaded after MFMA consumption, ping-pong P LDS
// with compiler fences, setprio around MFMA clusters.
// ---------------------------------------------------------------------------
__global__ __launch_bounds__(64, 2) void attn_fwd(const u16* __restrict__ QKV,
                                                  const u16* __restrict__ VT,
                                                  u16* __restrict__ Z) {
  __shared__ __align__(16) u16 sP[2][2][16 * 72];   // [tile][pingpong]
  const int lane = threadIdx.x;
  const int lq = lane & 15, quad = lane >> 4;

  const int id   = blockIdx.x;             // 0..2047
  const int xcd  = id & 7;
  const int slot = id >> 3;                // 0..255 per XCD
  const int g    = xcd + 8 * (slot >> 6);  // combo 0..31
  const int s    = slot & 63;
  const int u    = (s < 32) ? (63 - s) : (s - 32);  // heavy+light pairing
  const int h = g & 15, b = g >> 4;
  const int qA = u * 32, qB = qA + 16;
  const int nchunk = u / 2 + 1;            // 64-key chunks

  const int RS = 3072;
  const u16* base = QKV + (size_t)b * 2048 * RS;
  const u16* Qb  = base + h * 64;
  const u16* Kb  = base + 1024 + h * 64;
  const u16* VTb = VT + (size_t)h * 64 * 4096 + (size_t)b * 2048;

  // Q frags (B-operand): lane holds Q[q+lq][d = 32*half + quad*8 + j]
  s8v qfA0 = *(const s8v*)&Qb[(size_t)(qA + lq) * RS + quad * 8];
  s8v qfA1 = *(const s8v*)&Qb[(size_t)(qA + lq) * RS + 32 + quad * 8];
  s8v qfB0 = *(const s8v*)&Qb[(size_t)(qB + lq) * RS + quad * 8];
  s8v qfB1 = *(const s8v*)&Qb[(size_t)(qB + lq) * RS + 32 + quad * 8];

  f4v zA[4] = {}, zB[4] = {};
  float mA = -3.0e38f, lA = 0.f, mB = -3.0e38f, lB = 0.f;

  s8v kf[8], vf[8];   // single buffers: K rows / V cols of the current chunk

#define LOADK(c_) do {                                                        \
    const int kk0_ = (c_) * 64;                                               \
    _Pragma("unroll")                                                         \
    for (int i_ = 0; i_ < 4; ++i_) {                                          \
      const u16* kr_ = &Kb[(size_t)(kk0_ + 16 * i_ + lq) * RS + quad * 8];    \
      kf[2 * i_]     = *(const s8v*)kr_;                                      \
      kf[2 * i_ + 1] = *(const s8v*)(kr_ + 32);                               \
    }                                                                         \
  } while (0)

#define LOADV(c_) do {                                                        \
    const int kk0_ = (c_) * 64;                                               \
    _Pragma("unroll")                                                         \
    for (int d_ = 0; d_ < 4; ++d_) {                                          \
      const u16* vr_ = &VTb[(size_t)(d_ * 16 + lq) * 4096 + kk0_ + quad * 8]; \
      vf[d_]     = *(const s8v*)vr_;                                          \
      vf[d_ + 4] = *(const s8v*)(vr_ + 32);                                   \
    }                                                                         \
  } while (0)

  // softmax of 64-key chunk c for one tile (swapped layout) + packed P write
  auto SMW = [&](int c, int qt0, float& mrow, float& lsum, f4v (&zacc)[4],
                 u16* sPt, f4v (&sc)[4]) {
    float sv[4][4];
    for (int i = 0; i < 4; ++i)
      for (int r = 0; r < 4; ++r) sv[i][r] = sc[i][r];
    if (c + 1 == nchunk) {              // only the last chunk crosses the diagonal
      const int kb = c * 64;
      for (int i = 0; i < 4; ++i)
        for (int r = 0; r < 4; ++r)
          if (kb + 16 * i + quad * 4 + r > qt0 + lq) sv[i][r] = -3.0e38f;
    }
    float lmax = sv[0][0];
    for (int i = 0; i < 4; ++i)
      for (int r = 0; r < 4; ++r) lmax = fmaxf(lmax, sv[i][r]);
    if (!__all(lmax <= mrow + 8.0f)) {  // defer-max, THR=8
      float t = lmax;
      t = fmaxf(t, __shfl_xor(t, 16, 64));
      t = fmaxf(t, __shfl_xor(t, 32, 64));
      float mnew = fmaxf(mrow, t);
      float al = __expf(mrow - mnew);
      mrow = mnew;
      lsum *= al;
      float alr[4];
      for (int r = 0; r < 4; ++r) alr[r] = __shfl(al, quad * 4 + r, 16);
      for (int dc = 0; dc < 4; ++dc)
        for (int r = 0; r < 4; ++r) zacc[dc][r] *= alr[r];
    }
    float acc = 0.f;
    float p[4][4];
    for (int i = 0; i < 4; ++i)
      for (int r = 0; r < 4; ++r) {
        p[i][r] = __expf(sv[i][r] - mrow);
        acc += p[i][r];
      }
    lsum += acc;
    for (int i = 0; i < 4; ++i) {
      uint2 w;
      w.x = pk2(p[i][0], p[i][1]);
      w.y = pk2(p[i][2], p[i][3]);
      *(uint2*)&sPt[lq * 72 + 16 * i + quad * 4] = w;
    }
  };

#define QK(aA_, aB_) do {                                                     \
    _Pragma("unroll")                                                         \
    for (int i_ = 0; i_ < 4; ++i_) {                                          \
      aA_[i_] = __builtin_amdgcn_mfma_f32_16x16x32_bf16(kf[2*i_],   qfA0, aA_[i_], 0, 0, 0); \
      aA_[i_] = __builtin_amdgcn_mfma_f32_16x16x32_bf16(kf[2*i_+1], qfA1, aA_[i_], 0, 0, 0); \
      aB_[i_] = __builtin_amdgcn_mfma_f32_16x16x32_bf16(kf[2*i_],   qfB0, aB_[i_], 0, 0, 0); \
      aB_[i_] = __builtin_amdgcn_mfma_f32_16x16x32_bf16(kf[2*i_+1], qfB1, aB_[i_], 0, 0, 0); \
    }                                                                         \
  } while (0)

  // PV from ping-pong buffer pb (P of the previous chunk) + current vf
  auto PV = [&](int pb) {
    s8v pA0 = *(const s8v*)&sP[0][pb][lq * 72 + quad * 8];
    s8v pA1 = *(const s8v*)&sP[0][pb][lq * 72 + 32 + quad * 8];
    s8v pB0 = *(const s8v*)&sP[1][pb][lq * 72 + quad * 8];
    s8v pB1 = *(const s8v*)&sP[1][pb][lq * 72 + 32 + quad * 8];
#pragma unroll
    for (int d_ = 0; d_ < 4; ++d_) {
      zA[d_] = __builtin_amdgcn_mfma_f32_16x16x32_bf16(pA0, vf[d_],     zA[d_], 0, 0, 0);
      zA[d_] = __builtin_amdgcn_mfma_f32_16x16x32_bf16(pA1, vf[d_ + 4], zA[d_], 0, 0, 0);
      zB[d_] = __builtin_amdgcn_mfma_f32_16x16x32_bf16(pB0, vf[d_],     zB[d_], 0, 0, 0);
      zB[d_] = __builtin_amdgcn_mfma_f32_16x16x32_bf16(pB1, vf[d_ + 4], zB[d_], 0, 0, 0);
    }
  };

  LOADK(0);
  { // chunk 0: QK + softmax + P write into buf 0 (PV deferred)
    f4v aA[4] = {}, aB[4] = {};
    __builtin_amdgcn_s_setprio(1);
    QK(aA, aB);
    __builtin_amdgcn_s_setprio(0);
    if (nchunk > 1) LOADK(1);
    LOADV(0);
    SMW(0, qA, mA, lA, zA, sP[0][0], aA);
    SMW(0, qB, mB, lB, zB, sP[1][0], aB);
    asm volatile("" ::: "memory");      // P(0) writes pinned before PV reads
  }

  for (int c = 1; c < nchunk; ++c) {
    f4v aA[4] = {}, aB[4] = {};
    __builtin_amdgcn_s_setprio(1);
    QK(aA, aB);                         // kf = K(c)
    PV((c + 1) & 1);                    // reads P(c-1) + vf = V(c-1)
    __builtin_amdgcn_s_setprio(0);
    asm volatile("" ::: "memory");      // PV reads pinned before SMW writes
    if (c + 1 < nchunk) LOADK(c + 1);   // safe: QK consumed kf at issue
    LOADV(c);                           // safe: PV consumed vf at issue
    SMW(c, qA, mA, lA, zA, sP[0][c & 1], aA);
    SMW(c, qB, mB, lB, zB, sP[1][c & 1], aB);
    asm volatile("" ::: "memory");      // P(c) writes pinned before next PV
  }

  { // drain: PV(nchunk-1) from the last-written buffer
    __builtin_amdgcn_s_setprio(1);
    PV((nchunk - 1) & 1);
    __builtin_amdgcn_s_setprio(0);
  }
#undef QK
#undef LOADK
#undef LOADV

  // one-time sum reduction across the 4 quad-lanes of each row
  lA += __shfl_xor(lA, 16, 64); lA += __shfl_xor(lA, 32, 64);
  lB += __shfl_xor(lB, 16, 64); lB += __shfl_xor(lB, 32, 64);
  float invA[4], invB[4];
  for (int r = 0; r < 4; ++r) {
    invA[r] = 1.0f / __shfl(lA, quad * 4 + r, 16);
    invB[r] = 1.0f / __shfl(lB, quad * 4 + r, 16);
  }
  for (int dc = 0; dc < 4; ++dc)
    for (int r = 0; r < 4; ++r) {
      size_t rowA = (size_t)b * 2048 + qA + quad * 4 + r;
      size_t rowB = (size_t)b * 2048 + qB + quad * 4 + r;
      Z[rowA * 1024 + h * 64 + dc * 16 + lq] = f2b(zA[dc][r] * invA[r]);
      Z[rowB * 1024 + h * 64 + dc * 16 + lq] = f2b(zB[dc][r] * invB[r]);
    }
}

// ---------------------------------------------------------------------------
// Launch
// ---------------------------------------------------------------------------
extern "C" void kernel_launch(void* const* d_in, const int* in_sizes, int n_in,
                              void* d_out, int out_size, void* d_ws, size_t ws_size,
                              hipStream_t stream) {
  const float* x  = (const float*)d_in[0];
  const float* WQ = (const float*)d_in[1];
  const float* bQ = (const float*)d_in[2];
  const float* WK = (const float*)d_in[3];
  const float* bK = (const float*)d_in[4];
  const float* WV = (const float*)d_in[5];
  const float* WO = (const float*)d_in[6];
  const float* bV = (const float*)d_in[7];
  const float* bO = (const float*)d_in[8];
  float* out = (float*)d_out;

  uint8_t* ws = (uint8_t*)d_ws;
  u16*   xb    = (u16*)(ws);                       //  8 MB  [4096][1024] bf16 x
  u16*   WTqkv = (u16*)(ws + 8388608);             //  6 MB
  u16*   WOT   = (u16*)(ws + 14680064);            //  2 MB
  u16*   QKV   = (u16*)(ws + 16777216);            // 24 MB (V third unused now)
  u16*   Zb    = (u16*)(ws + 41943040);            //  8 MB
  float* bqkv  = (float*)(ws + 50331648);          // 12 KB
  float* bsum  = (float*)(ws + 50343936);          //  4 KB
  u16*   VTv   = (u16*)(ws + 50348032);            //  8 MB V^T (own region:
                                                   //  gemm1 reads xb while
                                                   //  writing VTv)

  // fused prep: conv_x + 3x convT_w + convT_wo + conv_bias
  prep<<<5136, 256, 0, stream>>>(x, xb, WQ, WK, WV, WO, WTqkv, WOT,
                                 bQ, bK, bV, bO, bqkv, bsum);
  // QKV projection (Q cols pre-scaled by 0.125), fused V-transpose epilogue:
  // 128x128 tile, 768 blocks = exactly 3/CU
  gemm_bt<false, 128, 128, 256, true><<<dim3(24, 32), 256, 0, stream>>>(
      xb, WTqkv, bqkv, (void*)QKV, VTv, 3072, 1024, 1024);
  // attention: round-7 proven config, 2048 one-wave blocks
  attn_fwd<<<dim3(2048, 1, 1), 64, 0, stream>>>(QKV, VTv, Zb);
  // output projection: 128x64 tile, 512 blocks = 2/CU
  gemm_bt<true, 128, 64, 256, false><<<dim3(16, 32), 256, 0, stream>>>(
      Zb, WOT, bsum, (void*)out, nullptr, 1024, 1024, 0);
}

// Round 13
// 207.860 us; speedup vs baseline: 1.5921x; 1.0088x over previous
//
#include <hip/hip_runtime.h>
#include <cstdint>

typedef unsigned short u16;
typedef short s8v __attribute__((ext_vector_type(8)));
typedef float f4v __attribute__((ext_vector_type(4)));

// fp32 -> bf16 round-to-nearest-even (bit trick)
__device__ __forceinline__ u16 f2b(float f) {
  uint32_t u = __float_as_uint(f);
  u = (u + 0x7FFFu + ((u >> 16) & 1u)) >> 16;
  return (u16)u;
}

// pack two f32 -> bf16x2 (RNE) in one instruction (T12 recipe; no builtin)
__device__ __forceinline__ uint32_t pk2(float a, float b) {
  uint32_t r;
  asm("v_cvt_pk_bf16_f32 %0, %1, %2" : "=v"(r) : "v"(a), "v"(b));
  return r;
}

// async global->LDS, 16B per lane (wave-uniform LDS base + lane*16 layout)
__device__ __forceinline__ void gload16(const u16* g, u16* l) {
  __builtin_amdgcn_global_load_lds(
      (const __attribute__((address_space(1))) void*)g,
      (__attribute__((address_space(3))) void*)l, 16, 0, 0);
}

// ---------------------------------------------------------------------------
// Fused prep kernel
// blocks: [0,4096) conv_x | [4096,4864) convT_w | [4864,5120) convT_wo |
//         [5120,5136) conv_bias
// ---------------------------------------------------------------------------
__global__ void prep(const float* __restrict__ x, u16* __restrict__ xb,
                     const float* __restrict__ WQ, const float* __restrict__ WK,
                     const float* __restrict__ WV, const float* __restrict__ WO,
                     u16* __restrict__ WTqkv, u16* __restrict__ WOT,
                     const float* __restrict__ bQ, const float* __restrict__ bK,
                     const float* __restrict__ bV, const float* __restrict__ bO,
                     float* __restrict__ bqkv, float* __restrict__ bsum) {
  __shared__ u16 tile[64][65];
  const int bid = blockIdx.x;
  const int tid = threadIdx.x;

  if (bid < 4096) {                       // x fp32 -> bf16, 4 elems/thread
    int i = bid * 256 + tid;
    float4 v = ((const float4*)x)[i];
    uint2 o;
    o.x = (uint32_t)f2b(v.x) | ((uint32_t)f2b(v.y) << 16);
    o.y = (uint32_t)f2b(v.z) | ((uint32_t)f2b(v.w) << 16);
    ((uint2*)xb)[i] = o;
  } else if (bid < 4864) {                // W_{Q,K,V} -> WTqkv (B^T), 64x64 transpose
    int sub = bid - 4096;
    int w = sub >> 8, sub2 = sub & 255;
    const float* W = (w == 0) ? WQ : (w == 1) ? WK : WV;
    u16* dst = WTqkv + (size_t)w * 1024 * 1024;
    const int m0 = (sub2 & 15) * 64;
    const int h  = sub2 >> 4;
    const int c  = tid & 63;
    const int r4 = tid >> 6;
    const float* Wh = W + (size_t)h * 65536;
    for (int i = 0; i < 16; ++i) {
      int lm = i * 4 + r4;
      tile[lm][c] = f2b(Wh[(size_t)(m0 + lm) * 64 + c]);
    }
    __syncthreads();
    for (int i = 0; i < 16; ++i) {
      int dd = i * 4 + r4;
      dst[((size_t)h * 64 + dd) * 1024 + m0 + c] = tile[c][dd];
    }
  } else if (bid < 5120) {                // W_O flat [1024][1024] -> WOT[m][k]
    int sub = bid - 4864;
    const int k0 = (sub & 15) * 64;
    const int m0 = (sub >> 4) * 64;
    const int c  = tid & 63;
    const int r4 = tid >> 6;
    for (int i = 0; i < 16; ++i) {
      int lk = i * 4 + r4;
      tile[lk][c] = f2b(WO[(size_t)(k0 + lk) * 1024 + m0 + c]);
    }
    __syncthreads();
    for (int i = 0; i < 16; ++i) {
      int lm = i * 4 + r4;
      WOT[(size_t)(m0 + lm) * 1024 + k0 + c] = tile[c][lm];
    }
  } else {                                // biases
    int t = (bid - 5120) * 256 + tid;
    if (t < 1024)       bqkv[t] = bQ[t];
    else if (t < 2048)  bqkv[t] = bK[t - 1024];
    else if (t < 3072)  bqkv[t] = bV[t - 2048];
    else {
      int m = t - 3072;
      float s = 0.f;
      for (int hh = 0; hh < 16; ++hh) s += bO[hh * 1024 + m];
      bsum[m] = s;
    }
  }
}

// ---------------------------------------------------------------------------
// bf16 MFMA GEMM: C = (A * BT^T + bias[col]) * (col<scale_cols ? 0.125 : 1)
// BMxBN tile, BK in {32,64}, NTHR/64 waves, per-wave 64x(BN/2).
// BK=64 is staged as TWO independent BK=32 half-tiles (each gload16 wave-call
// writes one contiguous 1KB run -> m104 wave-uniform-dest rule holds), with
// 2 half-compute passes per barrier period: doubles MFMA density per barrier
// (8->16 for BN=64) and halves barrier count. Used for the out-projection
// only: its grid (512 = 2/CU) is not LDS-occupancy-bound, so the m132
// BK-unroll occupancy trap doesn't apply (gemm1 keeps BK=32 for that reason).
// 2-phase pipeline: STAGE(next) before ds_read+MFMA of current, one barrier
// per K-step.
//
// FUSE_VT (QKV projection only): blocks with n0 >= 2048 emit V columns
// TRANSPOSED to VTout[(h*64+d)][token] via an LDS bounce (stride 136).
// ---------------------------------------------------------------------------
template<bool OUT_F32, int BM, int BN, int NTHR, bool FUSE_VT, int BK>
__global__ void gemm_bt(const u16* __restrict__ A, const u16* __restrict__ BT,
                        const float* __restrict__ bias, void* __restrict__ Cout,
                        u16* __restrict__ VTout, int N, int K, int scale_cols) {
  constexpr int NW = NTHR / 64;
  constexpr int WM = NW / 2;
  constexpr int NJ = BN / 32;
  constexpr int NH = BK / 32;            // half-tiles per K-step
  constexpr int ASEG = BM * 4 / NTHR;    // A staging segs/thread per half
  constexpr int BSEG = BN * 4 / NTHR;    // B staging segs/thread per half
  constexpr int STG_U16 = 2 * NH * (BM + BN) * 32;
  constexpr int CT_STRIDE = BM + 8;      // 136 for BM=128
  constexpr int SMEM_U16 = (FUSE_VT && BN * CT_STRIDE > STG_U16)
                               ? BN * CT_STRIDE : STG_U16;
  static_assert(BM / WM == 64, "per-wave rows must be 64");
  static_assert(BM * 4 % NTHR == 0 && BN * 4 % NTHR == 0, "staging divisibility");

  __shared__ __align__(16) u16 smem[SMEM_U16];
  u16* sA = smem;                        // [2][NH][BM*32]
  u16* sB = smem + 2 * NH * BM * 32;     // [2][NH][BN*32]

  const int tid  = threadIdx.x;
  const int lane = tid & 63, wave = tid >> 6;
  const int wm = wave >> 1, wn = wave & 1;
  const int lq = lane & 15, quad = lane >> 4;
  const int m0 = blockIdx.y * BM, n0 = blockIdx.x * BN;

  f4v acc[4][NJ] = {};

  auto STAGE = [&](int buf, int k0) {
    for (int hh = 0; hh < NH; ++hh) {
      for (int i = 0; i < ASEG; ++i) {
        int s = tid + i * NTHR;
        int row = s >> 2, part = s & 3;
        gload16(A + (size_t)(m0 + row) * K + k0 + hh * 32 + part * 8,
                &sA[(buf * NH + hh) * BM * 32 + s * 8]);
      }
      for (int i = 0; i < BSEG; ++i) {
        int s = tid + i * NTHR;
        int row = s >> 2, part = s & 3;
        gload16(BT + (size_t)(n0 + row) * K + k0 + hh * 32 + part * 8,
                &sB[(buf * NH + hh) * BN * 32 + s * 8]);
      }
    }
  };

  STAGE(0, 0);
  __syncthreads();                       // compiler drains vmcnt before barrier
  int cur = 0;
  for (int k0 = 0; k0 < K; k0 += BK) {
    if (k0 + BK < K) STAGE(cur ^ 1, k0 + BK);   // issue next-tile loads FIRST
    for (int hh = 0; hh < NH; ++hh) {
      s8v af[4], bfr[NJ];
      for (int i = 0; i < 4; ++i)
        af[i]  = *(const s8v*)&sA[(cur * NH + hh) * BM * 32 +
                                  (wm * 64 + i * 16 + lq) * 32 + quad * 8];
      for (int j = 0; j < NJ; ++j)
        bfr[j] = *(const s8v*)&sB[(cur * NH + hh) * BN * 32 +
                                  (wn * (BN / 2) + j * 16 + lq) * 32 + quad * 8];
      for (int i = 0; i < 4; ++i)
        for (int j = 0; j < NJ; ++j)
          acc[i][j] = __builtin_amdgcn_mfma_f32_16x16x32_bf16(af[i], bfr[j], acc[i][j], 0, 0, 0);
    }
    __syncthreads();                     // next-tile loads overlapped the MFMAs
    cur ^= 1;
  }

  if (FUSE_VT && n0 >= 2048) {
    // V columns: emit transposed to VTout[(vcol)][token] via LDS.
    const int vcol0 = n0 - 2048;
    u16* ct = smem;                      // staging LDS is dead past final barrier
    for (int i = 0; i < 4; ++i)
      for (int j = 0; j < NJ; ++j) {
        int row = wm * 64 + i * 16 + quad * 4;
        int col = wn * (BN / 2) + j * 16 + lq;
        float bb = bias[n0 + col];       // V cols: no 0.125 scale
        uint2 w;
        w.x = pk2(acc[i][j][0] + bb, acc[i][j][1] + bb);
        w.y = pk2(acc[i][j][2] + bb, acc[i][j][3] + bb);
        *(uint2*)&ct[col * CT_STRIDE + row] = w;   // ds_write_b64, 8B-aligned
      }
    __syncthreads();
    // cooperative write: thread t -> col cc = t>>1, half = t&1 (BM=128: 64 u16)
    if (tid < BN * 2) {
      int cc = tid >> 1, half = tid & 1;
      const uint4* src = (const uint4*)&ct[cc * CT_STRIDE + half * (BM / 2)];
      uint4* dst = (uint4*)&VTout[(size_t)(vcol0 + cc) * 4096 + m0 + half * (BM / 2)];
#pragma unroll
      for (int k = 0; k < BM / 16; ++k) dst[k] = src[k];
    }
    return;
  }

  for (int i = 0; i < 4; ++i)
    for (int j = 0; j < NJ; ++j) {
      int row = m0 + wm * 64 + i * 16 + quad * 4;
      int col = n0 + wn * (BN / 2) + j * 16 + lq;
      float bb = bias[col];
      float sc = (col < scale_cols) ? 0.125f : 1.0f;
      for (int r = 0; r < 4; ++r) {
        float v = (acc[i][j][r] + bb) * sc;
        if (OUT_F32) ((float*)Cout)[(size_t)(row + r) * N + col] = v;
        else         ((u16*)Cout)[(size_t)(row + r) * N + col] = f2b(v);
      }
    }
}

// ---------------------------------------------------------------------------
// Flash attention (causal). 1 wave, 2 adjacent 16-query tiles, KVBLK=64.
// Round-7 structure (best measured: 71us). Heavy+light CU pairing, single
// K/V register buffers reloaded after MFMA consumption, ping-pong P LDS
// with compiler fences, setprio around MFMA clusters.
// ---------------------------------------------------------------------------
__global__ __launch_bounds__(64, 2) void attn_fwd(const u16* __restrict__ QKV,
                                                  const u16* __restrict__ VT,
                                                  u16* __restrict__ Z) {
  __shared__ __align__(16) u16 sP[2][2][16 * 72];   // [tile][pingpong]
  const int lane = threadIdx.x;
  const int lq = lane & 15, quad = lane >> 4;

  const int id   = blockIdx.x;             // 0..2047
  const int xcd  = id & 7;
  const int slot = id >> 3;                // 0..255 per XCD
  const int g    = xcd + 8 * (slot >> 6);  // combo 0..31
  const int s    = slot & 63;
  const int u    = (s < 32) ? (63 - s) : (s - 32);  // heavy+light pairing
  const int h = g & 15, b = g >> 4;
  const int qA = u * 32, qB = qA + 16;
  const int nchunk = u / 2 + 1;            // 64-key chunks

  const int RS = 3072;
  const u16* base = QKV + (size_t)b * 2048 * RS;
  const u16* Qb  = base + h * 64;
  const u16* Kb  = base + 1024 + h * 64;
  const u16* VTb = VT + (size_t)h * 64 * 4096 + (size_t)b * 2048;

  // Q frags (B-operand): lane holds Q[q+lq][d = 32*half + quad*8 + j]
  s8v qfA0 = *(const s8v*)&Qb[(size_t)(qA + lq) * RS + quad * 8];
  s8v qfA1 = *(const s8v*)&Qb[(size_t)(qA + lq) * RS + 32 + quad * 8];
  s8v qfB0 = *(const s8v*)&Qb[(size_t)(qB + lq) * RS + quad * 8];
  s8v qfB1 = *(const s8v*)&Qb[(size_t)(qB + lq) * RS + 32 + quad * 8];

  f4v zA[4] = {}, zB[4] = {};
  float mA = -3.0e38f, lA = 0.f, mB = -3.0e38f, lB = 0.f;

  s8v kf[8], vf[8];   // single buffers: K rows / V cols of the current chunk

#define LOADK(c_) do {                                                        \
    const int kk0_ = (c_) * 64;                                               \
    _Pragma("unroll")                                                         \
    for (int i_ = 0; i_ < 4; ++i_) {                                          \
      const u16* kr_ = &Kb[(size_t)(kk0_ + 16 * i_ + lq) * RS + quad * 8];    \
      kf[2 * i_]     = *(const s8v*)kr_;                                      \
      kf[2 * i_ + 1] = *(const s8v*)(kr_ + 32);                               \
    }                                                                         \
  } while (0)

#define LOADV(c_) do {                                                        \
    const int kk0_ = (c_) * 64;                                               \
    _Pragma("unroll")                                                         \
    for (int d_ = 0; d_ < 4; ++d_) {                                          \
      const u16* vr_ = &VTb[(size_t)(d_ * 16 + lq) * 4096 + kk0_ + quad * 8]; \
      vf[d_]     = *(const s8v*)vr_;                                          \
      vf[d_ + 4] = *(const s8v*)(vr_ + 32);                                   \
    }                                                                         \
  } while (0)

  // softmax of 64-key chunk c for one tile (swapped layout) + packed P write
  auto SMW = [&](int c, int qt0, float& mrow, float& lsum, f4v (&zacc)[4],
                 u16* sPt, f4v (&sc)[4]) {
    float sv[4][4];
    for (int i = 0; i < 4; ++i)
      for (int r = 0; r < 4; ++r) sv[i][r] = sc[i][r];
    if (c + 1 == nchunk) {              // only the last chunk crosses the diagonal
      const int kb = c * 64;
      for (int i = 0; i < 4; ++i)
        for (int r = 0; r < 4; ++r)
          if (kb + 16 * i + quad * 4 + r > qt0 + lq) sv[i][r] = -3.0e38f;
    }
    float lmax = sv[0][0];
    for (int i = 0; i < 4; ++i)
      for (int r = 0; r < 4; ++r) lmax = fmaxf(lmax, sv[i][r]);
    if (!__all(lmax <= mrow + 8.0f)) {  // defer-max, THR=8
      float t = lmax;
      t = fmaxf(t, __shfl_xor(t, 16, 64));
      t = fmaxf(t, __shfl_xor(t, 32, 64));
      float mnew = fmaxf(mrow, t);
      float al = __expf(mrow - mnew);
      mrow = mnew;
      lsum *= al;
      float alr[4];
      for (int r = 0; r < 4; ++r) alr[r] = __shfl(al, quad * 4 + r, 16);
      for (int dc = 0; dc < 4; ++dc)
        for (int r = 0; r < 4; ++r) zacc[dc][r] *= alr[r];
    }
    float acc = 0.f;
    float p[4][4];
    for (int i = 0; i < 4; ++i)
      for (int r = 0; r < 4; ++r) {
        p[i][r] = __expf(sv[i][r] - mrow);
        acc += p[i][r];
      }
    lsum += acc;
    for (int i = 0; i < 4; ++i) {
      uint2 w;
      w.x = pk2(p[i][0], p[i][1]);
      w.y = pk2(p[i][2], p[i][3]);
      *(uint2*)&sPt[lq * 72 + 16 * i + quad * 4] = w;
    }
  };

#define QK(aA_, aB_) do {                                                     \
    _Pragma("unroll")                                                         \
    for (int i_ = 0; i_ < 4; ++i_) {                                          \
      aA_[i_] = __builtin_amdgcn_mfma_f32_16x16x32_bf16(kf[2*i_],   qfA0, aA_[i_], 0, 0, 0); \
      aA_[i_] = __builtin_amdgcn_mfma_f32_16x16x32_bf16(kf[2*i_+1], qfA1, aA_[i_], 0, 0, 0); \
      aB_[i_] = __builtin_amdgcn_mfma_f32_16x16x32_bf16(kf[2*i_],   qfB0, aB_[i_], 0, 0, 0); \
      aB_[i_] = __builtin_amdgcn_mfma_f32_16x16x32_bf16(kf[2*i_+1], qfB1, aB_[i_], 0, 0, 0); \
    }                                                                         \
  } while (0)

  // PV from ping-pong buffer pb (P of the previous chunk) + current vf
  auto PV = [&](int pb) {
    s8v pA0 = *(const s8v*)&sP[0][pb][lq * 72 + quad * 8];
    s8v pA1 = *(const s8v*)&sP[0][pb][lq * 72 + 32 + quad * 8];
    s8v pB0 = *(const s8v*)&sP[1][pb][lq * 72 + quad * 8];
    s8v pB1 = *(const s8v*)&sP[1][pb][lq * 72 + 32 + quad * 8];
#pragma unroll
    for (int d_ = 0; d_ < 4; ++d_) {
      zA[d_] = __builtin_amdgcn_mfma_f32_16x16x32_bf16(pA0, vf[d_],     zA[d_], 0, 0, 0);
      zA[d_] = __builtin_amdgcn_mfma_f32_16x16x32_bf16(pA1, vf[d_ + 4], zA[d_], 0, 0, 0);
      zB[d_] = __builtin_amdgcn_mfma_f32_16x16x32_bf16(pB0, vf[d_],     zB[d_], 0, 0, 0);
      zB[d_] = __builtin_amdgcn_mfma_f32_16x16x32_bf16(pB1, vf[d_ + 4], zB[d_], 0, 0, 0);
    }
  };

  LOADK(0);
  { // chunk 0: QK + softmax + P write into buf 0 (PV deferred)
    f4v aA[4] = {}, aB[4] = {};
    __builtin_amdgcn_s_setprio(1);
    QK(aA, aB);
    __builtin_amdgcn_s_setprio(0);
    if (nchunk > 1) LOADK(1);
    LOADV(0);
    SMW(0, qA, mA, lA, zA, sP[0][0], aA);
    SMW(0, qB, mB, lB, zB, sP[1][0], aB);
    asm volatile("" ::: "memory");      // P(0) writes pinned before PV reads
  }

  for (int c = 1; c < nchunk; ++c) {
    f4v aA[4] = {}, aB[4] = {};
    __builtin_amdgcn_s_setprio(1);
    QK(aA, aB);                         // kf = K(c)
    PV((c + 1) & 1);                    // reads P(c-1) + vf = V(c-1)
    __builtin_amdgcn_s_setprio(0);
    asm volatile("" ::: "memory");      // PV reads pinned before SMW writes
    if (c + 1 < nchunk) LOADK(c + 1);   // safe: QK consumed kf at issue
    LOADV(c);                           // safe: PV consumed vf at issue
    SMW(c, qA, mA, lA, zA, sP[0][c & 1], aA);
    SMW(c, qB, mB, lB, zB, sP[1][c & 1], aB);
    asm volatile("" ::: "memory");      // P(c) writes pinned before next PV
  }

  { // drain: PV(nchunk-1) from the last-written buffer
    __builtin_amdgcn_s_setprio(1);
    PV((nchunk - 1) & 1);
    __builtin_amdgcn_s_setprio(0);
  }
#undef QK
#undef LOADK
#undef LOADV

  // one-time sum reduction across the 4 quad-lanes of each row
  lA += __shfl_xor(lA, 16, 64); lA += __shfl_xor(lA, 32, 64);
  lB += __shfl_xor(lB, 16, 64); lB += __shfl_xor(lB, 32, 64);
  float invA[4], invB[4];
  for (int r = 0; r < 4; ++r) {
    invA[r] = 1.0f / __shfl(lA, quad * 4 + r, 16);
    invB[r] = 1.0f / __shfl(lB, quad * 4 + r, 16);
  }
  for (int dc = 0; dc < 4; ++dc)
    for (int r = 0; r < 4; ++r) {
      size_t rowA = (size_t)b * 2048 + qA + quad * 4 + r;
      size_t rowB = (size_t)b * 2048 + qB + quad * 4 + r;
      Z[rowA * 1024 + h * 64 + dc * 16 + lq] = f2b(zA[dc][r] * invA[r]);
      Z[rowB * 1024 + h * 64 + dc * 16 + lq] = f2b(zB[dc][r] * invB[r]);
    }
}

// ---------------------------------------------------------------------------
// Launch
// ---------------------------------------------------------------------------
extern "C" void kernel_launch(void* const* d_in, const int* in_sizes, int n_in,
                              void* d_out, int out_size, void* d_ws, size_t ws_size,
                              hipStream_t stream) {
  const float* x  = (const float*)d_in[0];
  const float* WQ = (const float*)d_in[1];
  const float* bQ = (const float*)d_in[2];
  const float* WK = (const float*)d_in[3];
  const float* bK = (const float*)d_in[4];
  const float* WV = (const float*)d_in[5];
  const float* WO = (const float*)d_in[6];
  const float* bV = (const float*)d_in[7];
  const float* bO = (const float*)d_in[8];
  float* out = (float*)d_out;

  uint8_t* ws = (uint8_t*)d_ws;
  u16*   xb    = (u16*)(ws);                       //  8 MB  [4096][1024] bf16 x
  u16*   WTqkv = (u16*)(ws + 8388608);             //  6 MB
  u16*   WOT   = (u16*)(ws + 14680064);            //  2 MB
  u16*   QKV   = (u16*)(ws + 16777216);            // 24 MB (V third unused)
  u16*   Zb    = (u16*)(ws + 41943040);            //  8 MB
  float* bqkv  = (float*)(ws + 50331648);          // 12 KB
  float* bsum  = (float*)(ws + 50343936);          //  4 KB
  u16*   VTv   = (u16*)(ws + 50348032);            //  8 MB V^T (own region)

  // fused prep: conv_x + 3x convT_w + convT_wo + conv_bias
  prep<<<5136, 256, 0, stream>>>(x, xb, WQ, WK, WV, WO, WTqkv, WOT,
                                 bQ, bK, bV, bO, bqkv, bsum);
  // QKV projection (Q cols pre-scaled by 0.125), fused V-transpose epilogue:
  // 128x128 tile, BK=32, 768 blocks = exactly 3/CU
  gemm_bt<false, 128, 128, 256, true, 32><<<dim3(24, 32), 256, 0, stream>>>(
      xb, WTqkv, bqkv, (void*)QKV, VTv, 3072, 1024, 1024);
  // attention: round-7 proven config, 2048 one-wave blocks
  attn_fwd<<<dim3(2048, 1, 1), 64, 0, stream>>>(QKV, VTv, Zb);
  // output projection: 128x64 tile, BK=64 (2 half-stages), 512 blocks = 2/CU
  gemm_bt<true, 128, 64, 256, false, 64><<<dim3(16, 32), 256, 0, stream>>>(
      Zb, WOT, bsum, (void*)out, nullptr, 1024, 1024, 0);
}